// Round 7
// baseline (908.988 us; speedup 1.0000x reference)
//
#include <hip/hip_runtime.h>
#include <math.h>
#include <stdint.h>

// ---------------------------------------------------------------------------
// BasicTransformerBlock (B=2, H=W=64, C=320) — bf16 MFMA + LDS-staged flash.
// x2 = 2x + selfattn(x);  xn = GN(x2);  x3 = xn + crossattn(xn,ctx) + x2
// ff = geglu(x3);  out = ff @ Wd + bd + x3
// ---------------------------------------------------------------------------

typedef unsigned short u16;
typedef __attribute__((ext_vector_type(8))) short bf16x8;
typedef __attribute__((ext_vector_type(8))) unsigned short u16x8;
typedef __attribute__((ext_vector_type(4))) float f32x4;

constexpr int Bb = 2, Cc = 320;
constexpr int Nn = 64 * 64;                    // 4096 tokens per batch
constexpr int Mm = Bb * Nn;                    // 8192 rows
constexpr int GROUPS = 16, CG = Cc / GROUPS;   // 20
constexpr float EPS = 1e-3f;
constexpr int GN_SPLIT = 8;
constexpr int KVS = 4;                         // kv splits (flash)
constexpr int KVC = Nn / KVS;                  // 1024 kv rows per block
constexpr int KVT = 32;                        // kv rows per LDS tile
constexpr float THR = 8.f;                     // defer-max threshold (T13)

__device__ __forceinline__ u16 f2b(float f) {
  unsigned u = __float_as_uint(f);
  unsigned r = u + 0x7fffu + ((u >> 16) & 1u);
  return (u16)(r >> 16);
}
__device__ __forceinline__ float b2f(u16 h) {
  return __uint_as_float(((unsigned)h) << 16);
}

// ---------------- bf16 NT GEMM with fused epilogue --------------------------
// C = scale*(A@B^T) + bias + alpha1*R1 + R2 ; C is fp32 (F32OUT) or bf16.
// DUAL additionally writes bf16 copy to C2. z = blockIdx.z batch slice.
template <bool F32OUT, bool DUAL>
__global__ __launch_bounds__(256) void gemm_nt(
    const u16* __restrict__ A, int lda, long long aZ,
    const u16* __restrict__ B, int ldb, long long bZ,
    const float* __restrict__ bias,
    const float* __restrict__ R1, float alpha1,
    const float* __restrict__ R2,
    void* __restrict__ Cp, int ldc, long long cZ,
    u16* __restrict__ C2,
    int K, float scale) {
  const int z = blockIdx.z;
  A += (long long)z * aZ;
  B += (long long)z * bZ;
  const long long coffz = (long long)z * cZ;

  __shared__ __align__(16) u16 As[128][40];  // +8 pad: breaks bank conflicts
  __shared__ __align__(16) u16 Bs[64][40];

  const int tid = threadIdx.x;
  const int bm = blockIdx.y * 128, bn = blockIdx.x * 64;
  const int lane = tid & 63;
  const int wid = tid >> 6;
  const int wm = (wid >> 1) * 64, wn = (wid & 1) * 32;  // wave sub-tile origin
  const int lr = lane & 15, lk = (lane >> 4) * 8;       // frag row, k-off

  const int sr = tid >> 2;        // staging row 0..63
  const int sk = (tid & 3) * 8;   // staging k offset

  f32x4 acc[4][2] = {};

  const u16* Ap0 = A + (size_t)(bm + sr) * lda + sk;
  const u16* Ap1 = A + (size_t)(bm + 64 + sr) * lda + sk;
  const u16* Bp0 = B + (size_t)(bn + sr) * ldb + sk;

  for (int k0 = 0; k0 < K; k0 += 32) {
    *reinterpret_cast<u16x8*>(&As[sr][sk]) =
        *reinterpret_cast<const u16x8*>(Ap0 + k0);
    *reinterpret_cast<u16x8*>(&As[64 + sr][sk]) =
        *reinterpret_cast<const u16x8*>(Ap1 + k0);
    *reinterpret_cast<u16x8*>(&Bs[sr][sk]) =
        *reinterpret_cast<const u16x8*>(Bp0 + k0);
    __syncthreads();

    bf16x8 af[4], bfr[2];
#pragma unroll
    for (int i = 0; i < 4; ++i)
      af[i] = *reinterpret_cast<const bf16x8*>(&As[wm + i * 16 + lr][lk]);
#pragma unroll
    for (int j = 0; j < 2; ++j)
      bfr[j] = *reinterpret_cast<const bf16x8*>(&Bs[wn + j * 16 + lr][lk]);
#pragma unroll
    for (int i = 0; i < 4; ++i)
#pragma unroll
      for (int j = 0; j < 2; ++j)
        acc[i][j] = __builtin_amdgcn_mfma_f32_16x16x32_bf16(af[i], bfr[j],
                                                            acc[i][j], 0, 0, 0);
    __syncthreads();
  }

  float* Cf = (float*)Cp;
  u16* Cb = (u16*)Cp;
#pragma unroll
  for (int i = 0; i < 4; ++i)
#pragma unroll
    for (int j = 0; j < 2; ++j)
#pragma unroll
      for (int r = 0; r < 4; ++r) {
        // verified C/D layout: col = lane&15, row = (lane>>4)*4 + reg
        const int row = bm + wm + i * 16 + (lane >> 4) * 4 + r;
        const int col = bn + wn + j * 16 + lr;
        const long long off = (long long)row * ldc + col + coffz;
        float v = acc[i][j][r] * scale;
        if (bias) v += bias[col];
        if (R1) v += alpha1 * R1[off];
        if (R2) v += R2[off];
        if (F32OUT) Cf[off] = v; else Cb[off] = f2b(v);
        if (DUAL) C2[off] = f2b(v);
      }
}

// ---------------- fused flash attention (LDS-staged, swizzled K) ------------
// Per block: 64 q-rows (4 waves x 16 rows), kv chunk KVC, KVT-row LDS tiles.
// Ks is XOR-swizzled on 16B slots (slot ^= row&7) -> conflict-free b128 reads
// (row stride 640B == 0 mod 32 banks; 8-lane groups hit 8 distinct spans).
// Defer-max (THR): skip accO rescale unless tile max grows past m+THR.
__global__ __launch_bounds__(256, 3) void flash_k(
    const u16* __restrict__ qb, const u16* __restrict__ kb,
    const u16* __restrict__ vtb, float* __restrict__ pO,
    float* __restrict__ pml, float scale) {
  const int qt = blockIdx.x, s = blockIdx.y, b = blockIdx.z;
  const int tid = threadIdx.x, wave = tid >> 6, lane = tid & 63;
  const int lr = lane & 15, hi = lane >> 4;
  const int qrow = qt * 64 + wave * 16;  // within batch

  // LDS: 20480 + 25600 + 5120 = 51200 B -> 3 blocks/CU
  __shared__ __align__(16) u16 Ks[KVT * 320];   // swizzled
  __shared__ __align__(16) u16 Vts[Cc][40];     // stride 40: conflict-free
  __shared__ __align__(16) u16 plds[4][16][40];

  // Q strip 16x320 in registers (A-fragments)
  bf16x8 qreg[10];
  const long long qbase = ((long long)b * Nn + qrow + lr) * Cc;
#pragma unroll
  for (int ks = 0; ks < 10; ++ks)
    qreg[ks] = *reinterpret_cast<const bf16x8*>(qb + qbase + ks * 32 + hi * 8);

  f32x4 accO[20] = {};
  float m[4] = {-INFINITY, -INFINITY, -INFINITY, -INFINITY};
  float l[4] = {0.f, 0.f, 0.f, 0.f};

  const u16* kbb = kb + (long long)b * Nn * Cc;
  const u16* vtbb = vtb + (long long)b * Cc * Nn;
  const int kv0 = s * KVC;

  const int krow = tid >> 3;        // 0..31 (K staging row)
  const int kcb  = tid & 7;         // K staging 16B-chunk base
  for (int t = 0; t < KVC / KVT; ++t) {
    const int kvb = kv0 + t * KVT;
    // ---- issue global loads into regs (overlap prior compute until barrier)
    u16x8 kst[5], vst[5];
#pragma unroll
    for (int c = 0; c < 5; ++c)
      kst[c] = *reinterpret_cast<const u16x8*>(
          kbb + (long long)(kvb + krow) * Cc + (kcb + 8 * c) * 8);
#pragma unroll
    for (int c = 0; c < 5; ++c) {
      const int id = tid + 256 * c;  // 0..1279
      const int vr = id >> 2, vc = id & 3;
      vst[c] = *reinterpret_cast<const u16x8*>(
          vtbb + (long long)vr * Nn + kvb + vc * 8);
    }
    __syncthreads();  // A: all waves done reading LDS from iter t-1
#pragma unroll
    for (int c = 0; c < 5; ++c) {
      const int slot = (kcb + 8 * c) ^ (krow & 7);  // XOR swizzle
      *reinterpret_cast<u16x8*>(&Ks[krow * 320 + slot * 8]) = kst[c];
    }
#pragma unroll
    for (int c = 0; c < 5; ++c) {
      const int id = tid + 256 * c;
      const int vr = id >> 2, vc = id & 3;
      *reinterpret_cast<u16x8*>(&Vts[vr][vc * 8]) = vst[c];
    }
    __syncthreads();  // B: tile visible to all waves

    // ---- S = Q @ K^T for 16x32 strip ----
    f32x4 accS[2] = {};
    __builtin_amdgcn_s_setprio(1);
#pragma unroll
    for (int ks = 0; ks < 10; ++ks) {
#pragma unroll
      for (int j = 0; j < 2; ++j) {
        const int row = j * 16 + lr;
        const int slot = (ks * 4 + hi) ^ (row & 7);
        const bf16x8 bv =
            *reinterpret_cast<const bf16x8*>(&Ks[row * 320 + slot * 8]);
        accS[j] =
            __builtin_amdgcn_mfma_f32_16x16x32_bf16(qreg[ks], bv, accS[j], 0, 0, 0);
      }
    }
    __builtin_amdgcn_s_setprio(0);

    // ---- online softmax (rows = hi*4 + r), defer-max past THR ----
#pragma unroll
    for (int j = 0; j < 2; ++j)
#pragma unroll
      for (int r = 0; r < 4; ++r) accS[j][r] *= scale;

    float tm[4];
#pragma unroll
    for (int r = 0; r < 4; ++r) {
      float tv = fmaxf(accS[0][r], accS[1][r]);
#pragma unroll
      for (int off = 1; off < 16; off <<= 1) tv = fmaxf(tv, __shfl_xor(tv, off, 64));
      tm[r] = tv;
    }
    const bool grow = (tm[0] > m[0] + THR) | (tm[1] > m[1] + THR) |
                      (tm[2] > m[2] + THR) | (tm[3] > m[3] + THR);
    if (__any(grow)) {  // wave-uniform branch
      float resc[4];
#pragma unroll
      for (int r = 0; r < 4; ++r) {
        const float mn = fmaxf(m[r], tm[r]);
        resc[r] = __expf(m[r] - mn);
        m[r] = mn;
        l[r] *= resc[r];
      }
#pragma unroll
      for (int n = 0; n < 20; ++n)
#pragma unroll
        for (int r = 0; r < 4; ++r) accO[n][r] *= resc[r];
    }
#pragma unroll
    for (int r = 0; r < 4; ++r) {
      float ps = 0.f;
#pragma unroll
      for (int j = 0; j < 2; ++j) {
        const float p = __expf(accS[j][r] - m[r]);
        accS[j][r] = p;  // reuse as P
        ps += p;
      }
#pragma unroll
      for (int off = 1; off < 16; off <<= 1) ps += __shfl_xor(ps, off, 64);
      l[r] += ps;
    }

    // ---- P (acc layout) -> per-wave LDS tile -> A-fragments ----
#pragma unroll
    for (int j = 0; j < 2; ++j)
#pragma unroll
      for (int r = 0; r < 4; ++r)
        plds[wave][hi * 4 + r][j * 16 + lr] = f2b(accS[j][r]);
    // intra-wave RAW through LDS: same-lane alias forces ordering; per-wave
    // private tile — no barrier needed.

    // ---- O += P @ V (single k=32 slice) ----
    {
      const bf16x8 pa = *reinterpret_cast<const bf16x8*>(&plds[wave][lr][hi * 8]);
      __builtin_amdgcn_s_setprio(1);
#pragma unroll
      for (int n = 0; n < 20; ++n) {
        const bf16x8 bv =
            *reinterpret_cast<const bf16x8*>(&Vts[n * 16 + lr][hi * 8]);
        accO[n] = __builtin_amdgcn_mfma_f32_16x16x32_bf16(pa, bv, accO[n], 0, 0, 0);
      }
      __builtin_amdgcn_s_setprio(0);
    }
  }

  // ---- write unnormalized partials ----
  const long long obase = (((long long)(s * Bb + b)) * Nn + qrow) * Cc;
#pragma unroll
  for (int n = 0; n < 20; ++n)
#pragma unroll
    for (int r = 0; r < 4; ++r)
      pO[obase + (long long)(hi * 4 + r) * Cc + n * 16 + lr] = accO[n][r];
  if (lr == 0) {
#pragma unroll
    for (int r = 0; r < 4; ++r) {
      const long long mlb =
          (((long long)(s * Bb + b)) * Nn + qrow + hi * 4 + r) * 2;
      pml[mlb] = m[r];
      pml[mlb + 1] = l[r];
    }
  }
}

// ---------------- combine kv-split partials -> ob (bf16) --------------------
__global__ __launch_bounds__(256) void fcomb(const float* __restrict__ pO,
                                             const float* __restrict__ pml,
                                             u16* __restrict__ ob) {
  const int row = blockIdx.x * 8 + (threadIdx.x >> 5);  // 0..8191
  const int lane32 = threadIdx.x & 31;
  const int b = row >> 12, rb = row & 4095;
  float ms[KVS], ls[KVS], mm = -INFINITY;
#pragma unroll
  for (int s = 0; s < KVS; ++s) {
    const long long i = (((long long)(s * Bb + b)) * Nn + rb) * 2;
    ms[s] = pml[i];
    ls[s] = pml[i + 1];
    mm = fmaxf(mm, ms[s]);
  }
  float w[KVS], den = 0.f;
#pragma unroll
  for (int s = 0; s < KVS; ++s) {
    w[s] = __expf(ms[s] - mm);
    den += w[s] * ls[s];
  }
  const float inv = 1.0f / den;
#pragma unroll
  for (int k = 0; k < 3; ++k) {
    const int c = k * 128 + lane32 * 4;
    if (c < Cc) {
      float4 o = {0.f, 0.f, 0.f, 0.f};
#pragma unroll
      for (int s = 0; s < KVS; ++s) {
        const float4 v = *reinterpret_cast<const float4*>(
            pO + (((long long)(s * Bb + b)) * Nn + rb) * Cc + c);
        o.x += w[s] * v.x;
        o.y += w[s] * v.y;
        o.z += w[s] * v.z;
        o.w += w[s] * v.w;
      }
      ushort4 u;
      u.x = f2b(o.x * inv);
      u.y = f2b(o.y * inv);
      u.z = f2b(o.z * inv);
      u.w = f2b(o.w * inv);
      *reinterpret_cast<ushort4*>(ob + (long long)row * Cc + c) = u;
    }
  }
}

// ---------------- fp32 -> bf16 flat cast ------------------------------------
__global__ __launch_bounds__(256) void cast_b(const float* __restrict__ in,
                                              u16* __restrict__ out) {
  const size_t i = ((size_t)blockIdx.x * 256 + threadIdx.x) * 4;
  const float4 v = *reinterpret_cast<const float4*>(in + i);
  ushort4 o;
  o.x = f2b(v.x); o.y = f2b(v.y); o.z = f2b(v.z); o.w = f2b(v.w);
  *reinterpret_cast<ushort4*>(out + i) = o;
}

// ---------------- fp32 [R][C] -> bf16 [C][R] tiled transpose ----------------
__global__ __launch_bounds__(256) void tran_f2b(const float* __restrict__ in,
                                                u16* __restrict__ out, int R,
                                                int C, long long inZ,
                                                long long outZ) {
  in += (long long)blockIdx.z * inZ;
  out += (long long)blockIdx.z * outZ;
  __shared__ u16 t[32][33];
  const int c0 = blockIdx.x * 32, r0 = blockIdx.y * 32;
  const int tx = threadIdx.x, ty = threadIdx.y;  // 32 x 8
#pragma unroll
  for (int i = 0; i < 32; i += 8)
    t[ty + i][tx] = f2b(in[(size_t)(r0 + ty + i) * C + c0 + tx]);
  __syncthreads();
#pragma unroll
  for (int i = 0; i < 32; i += 8)
    out[(size_t)(c0 + ty + i) * R + r0 + tx] = t[tx][ty + i];
}

// ---------------- GroupNorm ------------------------------------------------
__global__ __launch_bounds__(256) void gn_stats(const float* __restrict__ x,
                                                float* __restrict__ partials) {
  const int s = blockIdx.x % GN_SPLIT;
  const int bg = blockIdx.x / GN_SPLIT;
  const int b = bg / GROUPS, g = bg % GROUPS;
  const int rows = Nn / GN_SPLIT;  // 512
  const float* base = x + (size_t)b * Nn * Cc + g * CG;
  float sum = 0.f, sq = 0.f;
  for (int i = threadIdx.x; i < rows * CG; i += 256) {
    const int r = i / CG, c = i % CG;
    const float v = base[(size_t)(s * rows + r) * Cc + c];
    sum += v; sq += v * v;
  }
#pragma unroll
  for (int off = 32; off >= 1; off >>= 1) {
    sum += __shfl_xor(sum, off, 64);
    sq += __shfl_xor(sq, off, 64);
  }
  __shared__ float rs[4], rq[4];
  const int tid = threadIdx.x;
  if ((tid & 63) == 0) { rs[tid >> 6] = sum; rq[tid >> 6] = sq; }
  __syncthreads();
  if (tid == 0) {
    partials[(bg * GN_SPLIT + s) * 2 + 0] = rs[0] + rs[1] + rs[2] + rs[3];
    partials[(bg * GN_SPLIT + s) * 2 + 1] = rq[0] + rq[1] + rq[2] + rq[3];
  }
}

__global__ __launch_bounds__(256) void gn_apply(
    const float* __restrict__ x, const float* __restrict__ partials,
    const float* __restrict__ gamma, const float* __restrict__ beta,
    float* __restrict__ xn, u16* __restrict__ xnb) {
  const size_t idx = (size_t)blockIdx.x * 256 + threadIdx.x;
  const int c = (int)(idx % Cc);
  const size_t row = idx / Cc;
  const int b = (int)(row / Nn);
  const int bg = b * GROUPS + c / CG;
  float sum = 0.f, sq = 0.f;
#pragma unroll
  for (int s = 0; s < GN_SPLIT; ++s) {
    sum += partials[(bg * GN_SPLIT + s) * 2 + 0];
    sq += partials[(bg * GN_SPLIT + s) * 2 + 1];
  }
  const float cnt = (float)Nn * CG;
  const float mean = sum / cnt;
  const float var = sq / cnt - mean * mean;
  const float r = rsqrtf(var + EPS);
  const float v = (x[idx] - mean) * r * gamma[c] + beta[c];
  xn[idx] = v;
  xnb[idx] = f2b(v);
}

// ---------------- GEGLU combine: ff = g1 * qgelu(g2) ------------------------
__global__ __launch_bounds__(256) void geglu_comb(const u16* __restrict__ g1,
                                                  const u16* __restrict__ g2,
                                                  u16* __restrict__ ff) {
  const size_t i = ((size_t)blockIdx.x * 256 + threadIdx.x) * 4;
  const ushort4 a = *reinterpret_cast<const ushort4*>(g1 + i);
  const ushort4 b = *reinterpret_cast<const ushort4*>(g2 + i);
  ushort4 o;
  float v1, v2;
  v1 = b2f(a.x); v2 = b2f(b.x);
  o.x = f2b(v1 * (v2 / (1.0f + __expf(-1.702f * v2))));
  v1 = b2f(a.y); v2 = b2f(b.y);
  o.y = f2b(v1 * (v2 / (1.0f + __expf(-1.702f * v2))));
  v1 = b2f(a.z); v2 = b2f(b.z);
  o.z = f2b(v1 * (v2 / (1.0f + __expf(-1.702f * v2))));
  v1 = b2f(a.w); v2 = b2f(b.w);
  o.w = f2b(v1 * (v2 / (1.0f + __expf(-1.702f * v2))));
  *reinterpret_cast<ushort4*>(ff + i) = o;
}

// ---------------------------------------------------------------------------
extern "C" void kernel_launch(void* const* d_in, const int* in_sizes, int n_in,
                              void* d_out, int out_size, void* d_ws,
                              size_t ws_size, hipStream_t stream) {
  const float* x   = (const float*)d_in[0];
  const float* ctx = (const float*)d_in[1];
  const float* W[8];
  const float* Bv[8];
  for (int i = 0; i < 8; ++i) {
    W[i]  = (const float*)d_in[2 + 2 * i];
    Bv[i] = (const float*)d_in[3 + 2 * i];
  }
  const float* gn_g = (const float*)d_in[18];
  const float* gn_b = (const float*)d_in[19];
  const float* gw   = (const float*)d_in[20];
  const float* gb   = (const float*)d_in[21];
  const float* dw   = (const float*)d_in[22];
  const float* db   = (const float*)d_in[23];
  float* out = (float*)d_out;

  // ---- workspace layout (bytes, 256-aligned) ----
  char* base = (char*)d_ws;
  size_t o = 0;
  auto alloc = [&](size_t bytes) {
    void* p = base + o;
    o = (o + bytes + 255) & ~(size_t)255;
    return p;
  };
  u16* wT[8];
  for (int i = 0; i < 8; ++i) wT[i] = (u16*)alloc(320 * 320 * 2);
  u16* gwT  = (u16*)alloc((size_t)2560 * 320 * 2);
  u16* dwT  = (u16*)alloc((size_t)320 * 1280 * 2);
  u16* xb   = (u16*)alloc((size_t)Mm * Cc * 2);
  u16* ctxb = (u16*)alloc((size_t)Mm * Cc * 2);
  float* x2 = (float*)alloc((size_t)Mm * Cc * 4);
  float* xn = (float*)alloc((size_t)Mm * Cc * 4);
  u16* xnb  = (u16*)alloc((size_t)Mm * Cc * 2);
  float* x3 = (float*)alloc((size_t)Mm * Cc * 4);
  u16* x3b  = (u16*)alloc((size_t)Mm * Cc * 2);
  float* stats = (float*)alloc(4096);
  // attention scratch (aliased by FFN buffers afterwards)
  const size_t SCRSZ = (size_t)20971520 + (size_t)KVS * Bb * Nn * Cc * 4 + 1048576;
  char* SCR = (char*)alloc(SCRSZ);
  u16* qb   = (u16*)SCR;                 //  5.24 MB
  u16* kb   = (u16*)(SCR + 5242880);     //  5.24 MB
  u16* vtb  = (u16*)(SCR + 10485760);    //  5.24 MB
  u16* ob   = (u16*)(SCR + 15728640);    //  5.24 MB
  char* REST = SCR + 20971520;
  float* vf  = (float*)REST;             // 10.49 MB (dead before flash)
  float* pO  = (float*)REST;             // 41.94 MB (flash partials, overlaps vf)
  float* pml = (float*)(REST + (size_t)KVS * Bb * Nn * Cc * 4);  // 256 KB
  // FFN aliases — all of SCR is dead once x3 is computed
  u16* g1b = (u16*)SCR;
  u16* g2b = (u16*)(SCR + 20971520);
  u16* ffb = (u16*)(SCR + 41943040);

  if (base == nullptr || ws_size < o) return;  // d_out stays poisoned

  const float scale = 1.0f / sqrtf((float)Cc);
  const long long NC = (long long)Nn * Cc;

  auto gemm_b = [&](const u16* A, int lda, long long aZ, const u16* B, int ldb,
                    long long bZ, const float* bias, u16* C, int ldc,
                    long long cZ, int Mr, int Nc, int K, float sc, int nz) {
    dim3 grid(Nc / 64, Mr / 128, nz);
    gemm_nt<false, false><<<grid, 256, 0, stream>>>(
        A, lda, aZ, B, ldb, bZ, bias, nullptr, 0.f, nullptr, C, ldc, cZ,
        nullptr, K, sc);
  };
  auto gemm_f = [&](const u16* A, int lda, const u16* B, int ldb,
                    const float* bias, const float* R1, float a1,
                    const float* R2, float* C, int ldc, int Mr, int Nc, int K) {
    dim3 grid(Nc / 64, Mr / 128, 1);
    gemm_nt<true, false><<<grid, 256, 0, stream>>>(
        A, lda, 0, B, ldb, 0, bias, R1, a1, R2, C, ldc, 0, nullptr, K, 1.f);
  };

  // ---- cast inputs & transpose weights ----
  cast_b<<<(Mm * Cc) / 1024, 256, 0, stream>>>(x, xb);
  cast_b<<<(Mm * Cc) / 1024, 256, 0, stream>>>(ctx, ctxb);
  for (int i = 0; i < 8; ++i)
    tran_f2b<<<dim3(10, 10, 1), dim3(32, 8), 0, stream>>>(W[i], wT[i], 320, 320, 0, 0);
  tran_f2b<<<dim3(80, 10, 1), dim3(32, 8), 0, stream>>>(gw, gwT, 320, 2560, 0, 0);
  tran_f2b<<<dim3(10, 40, 1), dim3(32, 8), 0, stream>>>(dw, dwT, 1280, 320, 0, 0);

  auto attention = [&](const u16* qsrc, const u16* kv, int wi) {
    gemm_b(qsrc, Cc, 0, wT[wi + 0], Cc, 0, Bv[wi + 0], qb, Cc, 0, Mm, Cc, Cc, 1.f, 1);
    gemm_b(kv,   Cc, 0, wT[wi + 1], Cc, 0, Bv[wi + 1], kb, Cc, 0, Mm, Cc, Cc, 1.f, 1);
    {
      dim3 grid(Cc / 64, Mm / 128, 1);
      gemm_nt<true, false><<<grid, 256, 0, stream>>>(
          kv, Cc, 0, wT[wi + 2], Cc, 0, Bv[wi + 2], nullptr, 0.f, nullptr, vf,
          Cc, 0, nullptr, Cc, 1.f);
    }
    tran_f2b<<<dim3(Cc / 32, Nn / 32, 2), dim3(32, 8), 0, stream>>>(
        vf, vtb, Nn, Cc, NC, NC);
    flash_k<<<dim3(Nn / 64, KVS, Bb), 256, 0, stream>>>(qb, kb, vtb, pO, pml,
                                                        scale);
    fcomb<<<Mm / 8, 256, 0, stream>>>(pO, pml, ob);
  };

  // ---- self-attention: x2 = o@Wp + bp + 2*x ----
  attention(xb, xb, 0);
  gemm_f(ob, Cc, wT[3], Cc, Bv[3], x, 2.0f, nullptr, x2, Cc, Mm, Cc, Cc);

  // ---- GroupNorm(x2) -> xn (fp32) + xnb (bf16) ----
  gn_stats<<<Bb * GROUPS * GN_SPLIT, 256, 0, stream>>>(x2, stats);
  gn_apply<<<(Mm * Cc) / 256, 256, 0, stream>>>(x2, stats, gn_g, gn_b, xn, xnb);

  // ---- cross-attention: x3 = o@Wp2 + bp2 + xn + x2 (fp32 + bf16 dual) ----
  attention(xnb, ctxb, 4);
  {
    dim3 grid(Cc / 64, Mm / 128, 1);
    gemm_nt<true, true><<<grid, 256, 0, stream>>>(
        ob, Cc, 0, wT[7], Cc, 0, Bv[7], xn, 1.0f, x2, x3, Cc, 0, x3b, Cc, 1.f);
  }

  // ---- GEGLU FFN ----
  gemm_b(x3b, Cc, 0, gwT, Cc, 0, gb, g1b, 1280, 0, Mm, 1280, Cc, 1.f, 1);
  gemm_b(x3b, Cc, 0, gwT + (size_t)1280 * 320, Cc, 0, gb + 1280, g2b, 1280, 0,
         Mm, 1280, Cc, 1.f, 1);
  geglu_comb<<<(int)(((size_t)Mm * 1280) / 1024), 256, 0, stream>>>(g1b, g2b, ffb);
  gemm_f(ffb, 1280, dwT, 1280, db, x3, 1.0f, nullptr, out, Cc, Mm, Cc, 1280);
}

// Round 8
// 607.040 us; speedup vs baseline: 1.4974x; 1.4974x over previous
//
#include <hip/hip_runtime.h>
#include <math.h>
#include <stdint.h>

// ---------------------------------------------------------------------------
// BasicTransformerBlock (B=2, H=W=64, C=320) — bf16 MFMA + LDS-staged flash.
// x2 = 2x + selfattn(x);  xn = GN(x2);  x3 = xn + crossattn(xn,ctx) + x2
// ff = geglu(x3);  out = ff @ Wd + bd + x3
// ---------------------------------------------------------------------------

typedef unsigned short u16;
typedef __attribute__((ext_vector_type(8))) short bf16x8;
typedef __attribute__((ext_vector_type(8))) unsigned short u16x8;
typedef __attribute__((ext_vector_type(4))) float f32x4;

constexpr int Bb = 2, Cc = 320;
constexpr int Nn = 64 * 64;                    // 4096 tokens per batch
constexpr int Mm = Bb * Nn;                    // 8192 rows
constexpr int GROUPS = 16, CG = Cc / GROUPS;   // 20
constexpr float EPS = 1e-3f;
constexpr int GN_SPLIT = 8;
constexpr int KVS = 4;                         // kv splits (flash)
constexpr int KVC = Nn / KVS;                  // 1024 kv rows per block
constexpr int KVT = 32;                        // kv rows per LDS tile
constexpr float THR = 8.f;                     // defer-max threshold (T13)

__device__ __forceinline__ u16 f2b(float f) {
  unsigned u = __float_as_uint(f);
  unsigned r = u + 0x7fffu + ((u >> 16) & 1u);
  return (u16)(r >> 16);
}
__device__ __forceinline__ float b2f(u16 h) {
  return __uint_as_float(((unsigned)h) << 16);
}

// ---------------- bf16 NT GEMM with fused epilogue --------------------------
// C = scale*(A@B^T) + bias + alpha1*R1 + R2 ; C is fp32 (F32OUT) or bf16.
// DUAL additionally writes bf16 copy to C2. z = blockIdx.z batch slice.
template <bool F32OUT, bool DUAL>
__global__ __launch_bounds__(256) void gemm_nt(
    const u16* __restrict__ A, int lda, long long aZ,
    const u16* __restrict__ B, int ldb, long long bZ,
    const float* __restrict__ bias,
    const float* __restrict__ R1, float alpha1,
    const float* __restrict__ R2,
    void* __restrict__ Cp, int ldc, long long cZ,
    u16* __restrict__ C2,
    int K, float scale) {
  const int z = blockIdx.z;
  A += (long long)z * aZ;
  B += (long long)z * bZ;
  const long long coffz = (long long)z * cZ;

  __shared__ __align__(16) u16 As[128][40];  // +8 pad: breaks bank conflicts
  __shared__ __align__(16) u16 Bs[64][40];

  const int tid = threadIdx.x;
  const int bm = blockIdx.y * 128, bn = blockIdx.x * 64;
  const int lane = tid & 63;
  const int wid = tid >> 6;
  const int wm = (wid >> 1) * 64, wn = (wid & 1) * 32;  // wave sub-tile origin
  const int lr = lane & 15, lk = (lane >> 4) * 8;       // frag row, k-off

  const int sr = tid >> 2;        // staging row 0..63
  const int sk = (tid & 3) * 8;   // staging k offset

  f32x4 acc[4][2] = {};

  const u16* Ap0 = A + (size_t)(bm + sr) * lda + sk;
  const u16* Ap1 = A + (size_t)(bm + 64 + sr) * lda + sk;
  const u16* Bp0 = B + (size_t)(bn + sr) * ldb + sk;

  for (int k0 = 0; k0 < K; k0 += 32) {
    *reinterpret_cast<u16x8*>(&As[sr][sk]) =
        *reinterpret_cast<const u16x8*>(Ap0 + k0);
    *reinterpret_cast<u16x8*>(&As[64 + sr][sk]) =
        *reinterpret_cast<const u16x8*>(Ap1 + k0);
    *reinterpret_cast<u16x8*>(&Bs[sr][sk]) =
        *reinterpret_cast<const u16x8*>(Bp0 + k0);
    __syncthreads();

    bf16x8 af[4], bfr[2];
#pragma unroll
    for (int i = 0; i < 4; ++i)
      af[i] = *reinterpret_cast<const bf16x8*>(&As[wm + i * 16 + lr][lk]);
#pragma unroll
    for (int j = 0; j < 2; ++j)
      bfr[j] = *reinterpret_cast<const bf16x8*>(&Bs[wn + j * 16 + lr][lk]);
#pragma unroll
    for (int i = 0; i < 4; ++i)
#pragma unroll
      for (int j = 0; j < 2; ++j)
        acc[i][j] = __builtin_amdgcn_mfma_f32_16x16x32_bf16(af[i], bfr[j],
                                                            acc[i][j], 0, 0, 0);
    __syncthreads();
  }

  float* Cf = (float*)Cp;
  u16* Cb = (u16*)Cp;
#pragma unroll
  for (int i = 0; i < 4; ++i)
#pragma unroll
    for (int j = 0; j < 2; ++j)
#pragma unroll
      for (int r = 0; r < 4; ++r) {
        // verified C/D layout: col = lane&15, row = (lane>>4)*4 + reg
        const int row = bm + wm + i * 16 + (lane >> 4) * 4 + r;
        const int col = bn + wn + j * 16 + lr;
        const long long off = (long long)row * ldc + col + coffz;
        float v = acc[i][j][r] * scale;
        if (bias) v += bias[col];
        if (R1) v += alpha1 * R1[off];
        if (R2) v += R2[off];
        if (F32OUT) Cf[off] = v; else Cb[off] = f2b(v);
        if (DUAL) C2[off] = f2b(v);
      }
}

// ---------------- fused flash attention (LDS-staged, prefetched) ------------
// Per block: 64 q-rows (4 waves x 16 rows), kv chunk KVC, KVT-row LDS tiles.
// T14 split: tile t+1's global loads issue right after barrier B, hiding HBM
// latency under tile t's MFMA+softmax. Defer-max (THR) skips accO rescale
// unless the tile max grows past m+THR. launch_bounds(256,2): no VGPR squeeze
// (R7's ,3 caused spills: VGPR 84, hbm_bytes 2.3x — reverted).
__global__ __launch_bounds__(256, 2) void flash_k(
    const u16* __restrict__ qb, const u16* __restrict__ kb,
    const u16* __restrict__ vtb, float* __restrict__ pO,
    float* __restrict__ pml, float scale) {
  const int qt = blockIdx.x, s = blockIdx.y, b = blockIdx.z;
  const int tid = threadIdx.x, wave = tid >> 6, lane = tid & 63;
  const int lr = lane & 15, hi = lane >> 4;
  const int qrow = qt * 64 + wave * 16;  // within batch

  // LDS: 21504 + 25600 + 5120 = 52224 B
  __shared__ __align__(16) u16 Ks[KVT][336];
  __shared__ __align__(16) u16 Vts[Cc][40];
  __shared__ __align__(16) u16 plds[4][16][40];

  // Q strip 16x320 in registers (A-fragments)
  bf16x8 qreg[10];
  const long long qbase = ((long long)b * Nn + qrow + lr) * Cc;
#pragma unroll
  for (int ks = 0; ks < 10; ++ks)
    qreg[ks] = *reinterpret_cast<const bf16x8*>(qb + qbase + ks * 32 + hi * 8);

  f32x4 accO[20] = {};
  float m[4] = {-INFINITY, -INFINITY, -INFINITY, -INFINITY};
  float l[4] = {0.f, 0.f, 0.f, 0.f};

  const u16* kbb = kb + (long long)b * Nn * Cc;
  const u16* vtbb = vtb + (long long)b * Cc * Nn;
  const int kv0 = s * KVC;

  const int krow = tid >> 3;  // 0..31 (K staging row)
  const int kcb = tid & 7;    // K staging 16B-chunk base
  u16x8 kst[5], vst[5];       // staging regs, live across compute (T14)

  auto issue = [&](int t) {
    const int kvb = kv0 + t * KVT;
#pragma unroll
    for (int c = 0; c < 5; ++c)
      kst[c] = *reinterpret_cast<const u16x8*>(
          kbb + (long long)(kvb + krow) * Cc + (kcb + 8 * c) * 8);
#pragma unroll
    for (int c = 0; c < 5; ++c) {
      const int id = tid + 256 * c;  // 0..1279
      const int vr = id >> 2, vc = id & 3;
      vst[c] = *reinterpret_cast<const u16x8*>(
          vtbb + (long long)vr * Nn + kvb + vc * 8);
    }
  };

  issue(0);
  constexpr int NT = KVC / KVT;  // 32
  for (int t = 0; t < NT; ++t) {
    __syncthreads();  // A: all waves done reading LDS tile t-1
#pragma unroll
    for (int c = 0; c < 5; ++c)
      *reinterpret_cast<u16x8*>(&Ks[krow][(kcb + 8 * c) * 8]) = kst[c];
#pragma unroll
    for (int c = 0; c < 5; ++c) {
      const int id = tid + 256 * c;
      const int vr = id >> 2, vc = id & 3;
      *reinterpret_cast<u16x8*>(&Vts[vr][vc * 8]) = vst[c];
    }
    __syncthreads();  // B: tile visible to all waves

    if (t + 1 < NT) issue(t + 1);  // prefetch: latency hides under compute

    // ---- S = Q @ K^T for 16x32 strip ----
    f32x4 accS[2] = {};
    __builtin_amdgcn_s_setprio(1);
#pragma unroll
    for (int ks = 0; ks < 10; ++ks) {
#pragma unroll
      for (int j = 0; j < 2; ++j) {
        const bf16x8 bv =
            *reinterpret_cast<const bf16x8*>(&Ks[j * 16 + lr][ks * 32 + hi * 8]);
        accS[j] =
            __builtin_amdgcn_mfma_f32_16x16x32_bf16(qreg[ks], bv, accS[j], 0, 0, 0);
      }
    }
    __builtin_amdgcn_s_setprio(0);

    // ---- online softmax (rows = hi*4 + r), defer-max past THR ----
#pragma unroll
    for (int j = 0; j < 2; ++j)
#pragma unroll
      for (int r = 0; r < 4; ++r) accS[j][r] *= scale;

    float tm[4];
#pragma unroll
    for (int r = 0; r < 4; ++r) {
      float tv = fmaxf(accS[0][r], accS[1][r]);
#pragma unroll
      for (int off = 1; off < 16; off <<= 1) tv = fmaxf(tv, __shfl_xor(tv, off, 64));
      tm[r] = tv;
    }
    const bool grow = (tm[0] > m[0] + THR) | (tm[1] > m[1] + THR) |
                      (tm[2] > m[2] + THR) | (tm[3] > m[3] + THR);
    if (__any(grow)) {  // wave-uniform branch
      float resc[4];
#pragma unroll
      for (int r = 0; r < 4; ++r) {
        const float mn = fmaxf(m[r], tm[r]);
        resc[r] = __expf(m[r] - mn);
        m[r] = mn;
        l[r] *= resc[r];
      }
#pragma unroll
      for (int n = 0; n < 20; ++n)
#pragma unroll
        for (int r = 0; r < 4; ++r) accO[n][r] *= resc[r];
    }
#pragma unroll
    for (int r = 0; r < 4; ++r) {
      float ps = 0.f;
#pragma unroll
      for (int j = 0; j < 2; ++j) {
        const float p = __expf(accS[j][r] - m[r]);
        accS[j][r] = p;  // reuse as P
        ps += p;
      }
#pragma unroll
      for (int off = 1; off < 16; off <<= 1) ps += __shfl_xor(ps, off, 64);
      l[r] += ps;
    }

    // ---- P (acc layout) -> per-wave LDS tile -> A-fragments ----
#pragma unroll
    for (int j = 0; j < 2; ++j)
#pragma unroll
      for (int r = 0; r < 4; ++r)
        plds[wave][hi * 4 + r][j * 16 + lr] = f2b(accS[j][r]);
    // intra-wave RAW through LDS: same-lane alias forces ordering; per-wave
    // private tile — no barrier needed.

    // ---- O += P @ V (single k=32 slice) ----
    {
      const bf16x8 pa = *reinterpret_cast<const bf16x8*>(&plds[wave][lr][hi * 8]);
      __builtin_amdgcn_s_setprio(1);
#pragma unroll
      for (int n = 0; n < 20; ++n) {
        const bf16x8 bv =
            *reinterpret_cast<const bf16x8*>(&Vts[n * 16 + lr][hi * 8]);
        accO[n] = __builtin_amdgcn_mfma_f32_16x16x32_bf16(pa, bv, accO[n], 0, 0, 0);
      }
      __builtin_amdgcn_s_setprio(0);
    }
  }

  // ---- write unnormalized partials ----
  const long long obase = (((long long)(s * Bb + b)) * Nn + qrow) * Cc;
#pragma unroll
  for (int n = 0; n < 20; ++n)
#pragma unroll
    for (int r = 0; r < 4; ++r)
      pO[obase + (long long)(hi * 4 + r) * Cc + n * 16 + lr] = accO[n][r];
  if (lr == 0) {
#pragma unroll
    for (int r = 0; r < 4; ++r) {
      const long long mlb =
          (((long long)(s * Bb + b)) * Nn + qrow + hi * 4 + r) * 2;
      pml[mlb] = m[r];
      pml[mlb + 1] = l[r];
    }
  }
}

// ---------------- combine kv-split partials -> ob (bf16) --------------------
__global__ __launch_bounds__(256) void fcomb(const float* __restrict__ pO,
                                             const float* __restrict__ pml,
                                             u16* __restrict__ ob) {
  const int row = blockIdx.x * 8 + (threadIdx.x >> 5);  // 0..8191
  const int lane32 = threadIdx.x & 31;
  const int b = row >> 12, rb = row & 4095;
  float ms[KVS], ls[KVS], mm = -INFINITY;
#pragma unroll
  for (int s = 0; s < KVS; ++s) {
    const long long i = (((long long)(s * Bb + b)) * Nn + rb) * 2;
    ms[s] = pml[i];
    ls[s] = pml[i + 1];
    mm = fmaxf(mm, ms[s]);
  }
  float w[KVS], den = 0.f;
#pragma unroll
  for (int s = 0; s < KVS; ++s) {
    w[s] = __expf(ms[s] - mm);
    den += w[s] * ls[s];
  }
  const float inv = 1.0f / den;
#pragma unroll
  for (int k = 0; k < 3; ++k) {
    const int c = k * 128 + lane32 * 4;
    if (c < Cc) {
      float4 o = {0.f, 0.f, 0.f, 0.f};
#pragma unroll
      for (int s = 0; s < KVS; ++s) {
        const float4 v = *reinterpret_cast<const float4*>(
            pO + (((long long)(s * Bb + b)) * Nn + rb) * Cc + c);
        o.x += w[s] * v.x;
        o.y += w[s] * v.y;
        o.z += w[s] * v.z;
        o.w += w[s] * v.w;
      }
      ushort4 u;
      u.x = f2b(o.x * inv);
      u.y = f2b(o.y * inv);
      u.z = f2b(o.z * inv);
      u.w = f2b(o.w * inv);
      *reinterpret_cast<ushort4*>(ob + (long long)row * Cc + c) = u;
    }
  }
}

// ---------------- fp32 -> bf16 flat cast ------------------------------------
__global__ __launch_bounds__(256) void cast_b(const float* __restrict__ in,
                                              u16* __restrict__ out) {
  const size_t i = ((size_t)blockIdx.x * 256 + threadIdx.x) * 4;
  const float4 v = *reinterpret_cast<const float4*>(in + i);
  ushort4 o;
  o.x = f2b(v.x); o.y = f2b(v.y); o.z = f2b(v.z); o.w = f2b(v.w);
  *reinterpret_cast<ushort4*>(out + i) = o;
}

// ---------------- fp32 [R][C] -> bf16 [C][R] tiled transpose ----------------
__global__ __launch_bounds__(256) void tran_f2b(const float* __restrict__ in,
                                                u16* __restrict__ out, int R,
                                                int C, long long inZ,
                                                long long outZ) {
  in += (long long)blockIdx.z * inZ;
  out += (long long)blockIdx.z * outZ;
  __shared__ u16 t[32][33];
  const int c0 = blockIdx.x * 32, r0 = blockIdx.y * 32;
  const int tx = threadIdx.x, ty = threadIdx.y;  // 32 x 8
#pragma unroll
  for (int i = 0; i < 32; i += 8)
    t[ty + i][tx] = f2b(in[(size_t)(r0 + ty + i) * C + c0 + tx]);
  __syncthreads();
#pragma unroll
  for (int i = 0; i < 32; i += 8)
    out[(size_t)(c0 + ty + i) * R + r0 + tx] = t[tx][ty + i];
}

// ---------------- GroupNorm ------------------------------------------------
__global__ __launch_bounds__(256) void gn_stats(const float* __restrict__ x,
                                                float* __restrict__ partials) {
  const int s = blockIdx.x % GN_SPLIT;
  const int bg = blockIdx.x / GN_SPLIT;
  const int b = bg / GROUPS, g = bg % GROUPS;
  const int rows = Nn / GN_SPLIT;  // 512
  const float* base = x + (size_t)b * Nn * Cc + g * CG;
  float sum = 0.f, sq = 0.f;
  for (int i = threadIdx.x; i < rows * CG; i += 256) {
    const int r = i / CG, c = i % CG;
    const float v = base[(size_t)(s * rows + r) * Cc + c];
    sum += v; sq += v * v;
  }
#pragma unroll
  for (int off = 32; off >= 1; off >>= 1) {
    sum += __shfl_xor(sum, off, 64);
    sq += __shfl_xor(sq, off, 64);
  }
  __shared__ float rs[4], rq[4];
  const int tid = threadIdx.x;
  if ((tid & 63) == 0) { rs[tid >> 6] = sum; rq[tid >> 6] = sq; }
  __syncthreads();
  if (tid == 0) {
    partials[(bg * GN_SPLIT + s) * 2 + 0] = rs[0] + rs[1] + rs[2] + rs[3];
    partials[(bg * GN_SPLIT + s) * 2 + 1] = rq[0] + rq[1] + rq[2] + rq[3];
  }
}

__global__ __launch_bounds__(256) void gn_apply(
    const float* __restrict__ x, const float* __restrict__ partials,
    const float* __restrict__ gamma, const float* __restrict__ beta,
    float* __restrict__ xn, u16* __restrict__ xnb) {
  const size_t idx = (size_t)blockIdx.x * 256 + threadIdx.x;
  const int c = (int)(idx % Cc);
  const size_t row = idx / Cc;
  const int b = (int)(row / Nn);
  const int bg = b * GROUPS + c / CG;
  float sum = 0.f, sq = 0.f;
#pragma unroll
  for (int s = 0; s < GN_SPLIT; ++s) {
    sum += partials[(bg * GN_SPLIT + s) * 2 + 0];
    sq += partials[(bg * GN_SPLIT + s) * 2 + 1];
  }
  const float cnt = (float)Nn * CG;
  const float mean = sum / cnt;
  const float var = sq / cnt - mean * mean;
  const float r = rsqrtf(var + EPS);
  const float v = (x[idx] - mean) * r * gamma[c] + beta[c];
  xn[idx] = v;
  xnb[idx] = f2b(v);
}

// ---------------- GEGLU combine: ff = g1 * qgelu(g2) ------------------------
__global__ __launch_bounds__(256) void geglu_comb(const u16* __restrict__ g1,
                                                  const u16* __restrict__ g2,
                                                  u16* __restrict__ ff) {
  const size_t i = ((size_t)blockIdx.x * 256 + threadIdx.x) * 4;
  const ushort4 a = *reinterpret_cast<const ushort4*>(g1 + i);
  const ushort4 b = *reinterpret_cast<const ushort4*>(g2 + i);
  ushort4 o;
  float v1, v2;
  v1 = b2f(a.x); v2 = b2f(b.x);
  o.x = f2b(v1 * (v2 / (1.0f + __expf(-1.702f * v2))));
  v1 = b2f(a.y); v2 = b2f(b.y);
  o.y = f2b(v1 * (v2 / (1.0f + __expf(-1.702f * v2))));
  v1 = b2f(a.z); v2 = b2f(b.z);
  o.z = f2b(v1 * (v2 / (1.0f + __expf(-1.702f * v2))));
  v1 = b2f(a.w); v2 = b2f(b.w);
  o.w = f2b(v1 * (v2 / (1.0f + __expf(-1.702f * v2))));
  *reinterpret_cast<ushort4*>(ff + i) = o;
}

// ---------------------------------------------------------------------------
extern "C" void kernel_launch(void* const* d_in, const int* in_sizes, int n_in,
                              void* d_out, int out_size, void* d_ws,
                              size_t ws_size, hipStream_t stream) {
  const float* x   = (const float*)d_in[0];
  const float* ctx = (const float*)d_in[1];
  const float* W[8];
  const float* Bv[8];
  for (int i = 0; i < 8; ++i) {
    W[i]  = (const float*)d_in[2 + 2 * i];
    Bv[i] = (const float*)d_in[3 + 2 * i];
  }
  const float* gn_g = (const float*)d_in[18];
  const float* gn_b = (const float*)d_in[19];
  const float* gw   = (const float*)d_in[20];
  const float* gb   = (const float*)d_in[21];
  const float* dw   = (const float*)d_in[22];
  const float* db   = (const float*)d_in[23];
  float* out = (float*)d_out;

  // ---- workspace layout (bytes, 256-aligned) ----
  char* base = (char*)d_ws;
  size_t o = 0;
  auto alloc = [&](size_t bytes) {
    void* p = base + o;
    o = (o + bytes + 255) & ~(size_t)255;
    return p;
  };
  u16* wT[8];
  for (int i = 0; i < 8; ++i) wT[i] = (u16*)alloc(320 * 320 * 2);
  u16* gwT  = (u16*)alloc((size_t)2560 * 320 * 2);
  u16* dwT  = (u16*)alloc((size_t)320 * 1280 * 2);
  u16* xb   = (u16*)alloc((size_t)Mm * Cc * 2);
  u16* ctxb = (u16*)alloc((size_t)Mm * Cc * 2);
  float* x2 = (float*)alloc((size_t)Mm * Cc * 4);
  float* xn = (float*)alloc((size_t)Mm * Cc * 4);
  u16* xnb  = (u16*)alloc((size_t)Mm * Cc * 2);
  float* x3 = (float*)alloc((size_t)Mm * Cc * 4);
  u16* x3b  = (u16*)alloc((size_t)Mm * Cc * 2);
  float* stats = (float*)alloc(4096);
  // attention scratch (aliased by FFN buffers afterwards)
  const size_t SCRSZ = (size_t)20971520 + (size_t)KVS * Bb * Nn * Cc * 4 + 1048576;
  char* SCR = (char*)alloc(SCRSZ);
  u16* qb   = (u16*)SCR;                 //  5.24 MB
  u16* kb   = (u16*)(SCR + 5242880);     //  5.24 MB
  u16* vtb  = (u16*)(SCR + 10485760);    //  5.24 MB
  u16* ob   = (u16*)(SCR + 15728640);    //  5.24 MB
  char* REST = SCR + 20971520;
  float* vf  = (float*)REST;             // 10.49 MB (dead before flash)
  float* pO  = (float*)REST;             // 41.94 MB (flash partials, overlaps vf)
  float* pml = (float*)(REST + (size_t)KVS * Bb * Nn * Cc * 4);  // 256 KB
  // FFN aliases — all of SCR is dead once x3 is computed
  u16* g1b = (u16*)SCR;
  u16* g2b = (u16*)(SCR + 20971520);
  u16* ffb = (u16*)(SCR + 41943040);

  if (base == nullptr || ws_size < o) return;  // d_out stays poisoned

  const float scale = 1.0f / sqrtf((float)Cc);
  const long long NC = (long long)Nn * Cc;

  auto gemm_b = [&](const u16* A, int lda, long long aZ, const u16* B, int ldb,
                    long long bZ, const float* bias, u16* C, int ldc,
                    long long cZ, int Mr, int Nc, int K, float sc, int nz) {
    dim3 grid(Nc / 64, Mr / 128, nz);
    gemm_nt<false, false><<<grid, 256, 0, stream>>>(
        A, lda, aZ, B, ldb, bZ, bias, nullptr, 0.f, nullptr, C, ldc, cZ,
        nullptr, K, sc);
  };
  auto gemm_f = [&](const u16* A, int lda, const u16* B, int ldb,
                    const float* bias, const float* R1, float a1,
                    const float* R2, float* C, int ldc, int Mr, int Nc, int K) {
    dim3 grid(Nc / 64, Mr / 128, 1);
    gemm_nt<true, false><<<grid, 256, 0, stream>>>(
        A, lda, 0, B, ldb, 0, bias, R1, a1, R2, C, ldc, 0, nullptr, K, 1.f);
  };

  // ---- cast inputs & transpose weights ----
  cast_b<<<(Mm * Cc) / 1024, 256, 0, stream>>>(x, xb);
  cast_b<<<(Mm * Cc) / 1024, 256, 0, stream>>>(ctx, ctxb);
  for (int i = 0; i < 8; ++i)
    tran_f2b<<<dim3(10, 10, 1), dim3(32, 8), 0, stream>>>(W[i], wT[i], 320, 320, 0, 0);
  tran_f2b<<<dim3(80, 10, 1), dim3(32, 8), 0, stream>>>(gw, gwT, 320, 2560, 0, 0);
  tran_f2b<<<dim3(10, 40, 1), dim3(32, 8), 0, stream>>>(dw, dwT, 1280, 320, 0, 0);

  auto attention = [&](const u16* qsrc, const u16* kv, int wi) {
    gemm_b(qsrc, Cc, 0, wT[wi + 0], Cc, 0, Bv[wi + 0], qb, Cc, 0, Mm, Cc, Cc, 1.f, 1);
    gemm_b(kv,   Cc, 0, wT[wi + 1], Cc, 0, Bv[wi + 1], kb, Cc, 0, Mm, Cc, Cc, 1.f, 1);
    {
      dim3 grid(Cc / 64, Mm / 128, 1);
      gemm_nt<true, false><<<grid, 256, 0, stream>>>(
          kv, Cc, 0, wT[wi + 2], Cc, 0, Bv[wi + 2], nullptr, 0.f, nullptr, vf,
          Cc, 0, nullptr, Cc, 1.f);
    }
    tran_f2b<<<dim3(Cc / 32, Nn / 32, 2), dim3(32, 8), 0, stream>>>(
        vf, vtb, Nn, Cc, NC, NC);
    flash_k<<<dim3(Nn / 64, KVS, Bb), 256, 0, stream>>>(qb, kb, vtb, pO, pml,
                                                        scale);
    fcomb<<<Mm / 8, 256, 0, stream>>>(pO, pml, ob);
  };

  // ---- self-attention: x2 = o@Wp + bp + 2*x ----
  attention(xb, xb, 0);
  gemm_f(ob, Cc, wT[3], Cc, Bv[3], x, 2.0f, nullptr, x2, Cc, Mm, Cc, Cc);

  // ---- GroupNorm(x2) -> xn (fp32) + xnb (bf16) ----
  gn_stats<<<Bb * GROUPS * GN_SPLIT, 256, 0, stream>>>(x2, stats);
  gn_apply<<<(Mm * Cc) / 256, 256, 0, stream>>>(x2, stats, gn_g, gn_b, xn, xnb);

  // ---- cross-attention: x3 = o@Wp2 + bp2 + xn + x2 (fp32 + bf16 dual) ----
  attention(xnb, ctxb, 4);
  {
    dim3 grid(Cc / 64, Mm / 128, 1);
    gemm_nt<true, true><<<grid, 256, 0, stream>>>(
        ob, Cc, 0, wT[7], Cc, 0, Bv[7], xn, 1.0f, x2, x3, Cc, 0, x3b, Cc, 1.f);
  }

  // ---- GEGLU FFN ----
  gemm_b(x3b, Cc, 0, gwT, Cc, 0, gb, g1b, 1280, 0, Mm, 1280, Cc, 1.f, 1);
  gemm_b(x3b, Cc, 0, gwT + (size_t)1280 * 320, Cc, 0, gb + 1280, g2b, 1280, 0,
         Mm, 1280, Cc, 1.f, 1);
  geglu_comb<<<(int)(((size_t)Mm * 1280) / 1024), 256, 0, stream>>>(g1b, g2b, ffb);
  gemm_f(ffb, 1280, dwT, 1280, db, x3, 1.0f, nullptr, out, Cc, Mm, Cc, 1280);
}

// Round 9
// 551.800 us; speedup vs baseline: 1.6473x; 1.1001x over previous
//
#include <hip/hip_runtime.h>
#include <math.h>
#include <stdint.h>

// ---------------------------------------------------------------------------
// BasicTransformerBlock (B=2, H=W=64, C=320) — bf16 MFMA, fused projections,
// LDS-staged prefetched flash attention.
// x2 = 2x + selfattn(x);  xn = GN(x2);  x3 = xn + crossattn(xn,ctx) + x2
// ff = geglu(x3);  out = ff @ Wd + bd + x3
// ---------------------------------------------------------------------------

typedef unsigned short u16;
typedef __attribute__((ext_vector_type(8))) short bf16x8;
typedef __attribute__((ext_vector_type(8))) unsigned short u16x8;
typedef __attribute__((ext_vector_type(4))) float f32x4;

constexpr int Bb = 2, Cc = 320;
constexpr int Nn = 64 * 64;                    // 4096 tokens per batch
constexpr int Mm = Bb * Nn;                    // 8192 rows
constexpr int GROUPS = 16, CG = Cc / GROUPS;   // 20
constexpr float EPS = 1e-3f;
constexpr int GN_SPLIT = 8;
constexpr int KVS = 4;                         // kv splits (flash)
constexpr int KVC = Nn / KVS;                  // 1024 kv rows per block
constexpr int KVT = 32;                        // kv rows per LDS tile
constexpr float THR = 8.f;                     // defer-max threshold (T13)

__device__ __forceinline__ u16 f2b(float f) {
  unsigned u = __float_as_uint(f);
  unsigned r = u + 0x7fffu + ((u >> 16) & 1u);
  return (u16)(r >> 16);
}
__device__ __forceinline__ float b2f(u16 h) {
  return __uint_as_float(((unsigned)h) << 16);
}

// ---------------- bf16 NT GEMM with fused epilogue --------------------------
// C = scale*(A@B^T) + bias + alpha1*R1 + R2 ; C fp32 (F32OUT) or bf16.
// DUAL: extra bf16 copy to C2. VTS: cols >= vtc0 are written TRANSPOSED bf16
// into VT as [b][c][row%Nn] (per-lane 4 contiguous rows = one ushort4 store).
template <bool F32OUT, bool DUAL, bool VTS>
__global__ __launch_bounds__(256) void gemm_nt(
    const u16* __restrict__ A, int lda, long long aZ,
    const u16* __restrict__ B, int ldb, long long bZ,
    const float* __restrict__ bias,
    const float* __restrict__ R1, float alpha1,
    const float* __restrict__ R2,
    void* __restrict__ Cp, int ldc, long long cZ,
    u16* __restrict__ C2,
    u16* __restrict__ VT, int vtc0,
    int K, float scale) {
  const int z = blockIdx.z;
  A += (long long)z * aZ;
  B += (long long)z * bZ;
  const long long coffz = (long long)z * cZ;

  __shared__ __align__(16) u16 As[128][40];  // +8 pad: breaks bank conflicts
  __shared__ __align__(16) u16 Bs[64][40];

  const int tid = threadIdx.x;
  const int bm = blockIdx.y * 128, bn = blockIdx.x * 64;
  const int lane = tid & 63;
  const int wid = tid >> 6;
  const int wm = (wid >> 1) * 64, wn = (wid & 1) * 32;  // wave sub-tile origin
  const int lr = lane & 15, lk = (lane >> 4) * 8;       // frag row, k-off

  const int sr = tid >> 2;        // staging row 0..63
  const int sk = (tid & 3) * 8;   // staging k offset

  f32x4 acc[4][2] = {};

  const u16* Ap0 = A + (size_t)(bm + sr) * lda + sk;
  const u16* Ap1 = A + (size_t)(bm + 64 + sr) * lda + sk;
  const u16* Bp0 = B + (size_t)(bn + sr) * ldb + sk;

  for (int k0 = 0; k0 < K; k0 += 32) {
    *reinterpret_cast<u16x8*>(&As[sr][sk]) =
        *reinterpret_cast<const u16x8*>(Ap0 + k0);
    *reinterpret_cast<u16x8*>(&As[64 + sr][sk]) =
        *reinterpret_cast<const u16x8*>(Ap1 + k0);
    *reinterpret_cast<u16x8*>(&Bs[sr][sk]) =
        *reinterpret_cast<const u16x8*>(Bp0 + k0);
    __syncthreads();

    bf16x8 af[4], bfr[2];
#pragma unroll
    for (int i = 0; i < 4; ++i)
      af[i] = *reinterpret_cast<const bf16x8*>(&As[wm + i * 16 + lr][lk]);
#pragma unroll
    for (int j = 0; j < 2; ++j)
      bfr[j] = *reinterpret_cast<const bf16x8*>(&Bs[wn + j * 16 + lr][lk]);
#pragma unroll
    for (int i = 0; i < 4; ++i)
#pragma unroll
      for (int j = 0; j < 2; ++j)
        acc[i][j] = __builtin_amdgcn_mfma_f32_16x16x32_bf16(af[i], bfr[j],
                                                            acc[i][j], 0, 0, 0);
    __syncthreads();
  }

  float* Cf = (float*)Cp;
  u16* Cb = (u16*)Cp;
#pragma unroll
  for (int i = 0; i < 4; ++i)
#pragma unroll
    for (int j = 0; j < 2; ++j) {
      // verified C/D layout: col = lane&15, row = (lane>>4)*4 + reg
      const int col = bn + wn + j * 16 + lr;
      const int row0 = bm + wm + i * 16 + (lane >> 4) * 4;
      if (VTS && col >= vtc0) {
        const int c = col - vtc0;
        const int bz = row0 >> 12, rb = row0 & 4095;
        ushort4 u;
        u.x = f2b(acc[i][j][0] * scale + bias[col]);
        u.y = f2b(acc[i][j][1] * scale + bias[col]);
        u.z = f2b(acc[i][j][2] * scale + bias[col]);
        u.w = f2b(acc[i][j][3] * scale + bias[col]);
        *reinterpret_cast<ushort4*>(VT + ((long long)bz * Cc + c) * Nn + rb) = u;
      } else {
#pragma unroll
        for (int r = 0; r < 4; ++r) {
          const long long off = (long long)(row0 + r) * ldc + col + coffz;
          float v = acc[i][j][r] * scale;
          if (bias) v += bias[col];
          if (R1) v += alpha1 * R1[off];
          if (R2) v += R2[off];
          if (F32OUT) Cf[off] = v; else Cb[off] = f2b(v);
          if (DUAL) C2[off] = f2b(v);
        }
      }
    }
}

// ---------------- fused flash attention (LDS-staged, prefetched) ------------
// Per block: 64 q-rows (4 waves x 16 rows), kv chunk KVC, KVT-row LDS tiles.
// T14: tile t+1's global loads issue right after barrier B (latency hides
// under tile t's MFMA+softmax). Defer-max (THR) skips accO rescale unless the
// tile max grows past m+THR. launch_bounds(256,2): R7's ,3 spilled (VGPR 84).
__global__ __launch_bounds__(256, 2) void flash_k(
    const u16* __restrict__ q, int qlda, const u16* __restrict__ k, int klda,
    const u16* __restrict__ vtb, float* __restrict__ pO,
    float* __restrict__ pml, float scale) {
  const int qt = blockIdx.x, s = blockIdx.y, b = blockIdx.z;
  const int tid = threadIdx.x, wave = tid >> 6, lane = tid & 63;
  const int lr = lane & 15, hi = lane >> 4;
  const int qrow = qt * 64 + wave * 16;  // within batch

  // LDS: 21504 + 25600 + 5120 = 52224 B
  __shared__ __align__(16) u16 Ks[KVT][336];
  __shared__ __align__(16) u16 Vts[Cc][40];
  __shared__ __align__(16) u16 plds[4][16][40];

  // Q strip 16x320 in registers (A-fragments)
  bf16x8 qreg[10];
  const long long qbase = ((long long)b * Nn + qrow + lr) * qlda;
#pragma unroll
  for (int ks = 0; ks < 10; ++ks)
    qreg[ks] = *reinterpret_cast<const bf16x8*>(q + qbase + ks * 32 + hi * 8);

  f32x4 accO[20] = {};
  float m[4] = {-INFINITY, -INFINITY, -INFINITY, -INFINITY};
  float l[4] = {0.f, 0.f, 0.f, 0.f};

  const u16* kbb = k + (long long)b * Nn * klda;
  const u16* vtbb = vtb + (long long)b * Cc * Nn;
  const int kv0 = s * KVC;

  const int krow = tid >> 3;  // 0..31 (K staging row)
  const int kcb = tid & 7;    // K staging 16B-chunk base
  u16x8 kst[5], vst[5];       // staging regs, live across compute (T14)

  auto issue = [&](int t) {
    const int kvb = kv0 + t * KVT;
#pragma unroll
    for (int c = 0; c < 5; ++c)
      kst[c] = *reinterpret_cast<const u16x8*>(
          kbb + (long long)(kvb + krow) * klda + (kcb + 8 * c) * 8);
#pragma unroll
    for (int c = 0; c < 5; ++c) {
      const int id = tid + 256 * c;  // 0..1279
      const int vr = id >> 2, vc = id & 3;
      vst[c] = *reinterpret_cast<const u16x8*>(
          vtbb + (long long)vr * Nn + kvb + vc * 8);
    }
  };

  issue(0);
  constexpr int NT = KVC / KVT;  // 32
  for (int t = 0; t < NT; ++t) {
    __syncthreads();  // A: all waves done reading LDS tile t-1
#pragma unroll
    for (int c = 0; c < 5; ++c)
      *reinterpret_cast<u16x8*>(&Ks[krow][(kcb + 8 * c) * 8]) = kst[c];
#pragma unroll
    for (int c = 0; c < 5; ++c) {
      const int id = tid + 256 * c;
      const int vr = id >> 2, vc = id & 3;
      *reinterpret_cast<u16x8*>(&Vts[vr][vc * 8]) = vst[c];
    }
    __syncthreads();  // B: tile visible to all waves

    if (t + 1 < NT) issue(t + 1);  // prefetch: latency hides under compute

    // ---- S = Q @ K^T for 16x32 strip ----
    f32x4 accS[2] = {};
    __builtin_amdgcn_s_setprio(1);
#pragma unroll
    for (int ks = 0; ks < 10; ++ks) {
#pragma unroll
      for (int j = 0; j < 2; ++j) {
        const bf16x8 bv =
            *reinterpret_cast<const bf16x8*>(&Ks[j * 16 + lr][ks * 32 + hi * 8]);
        accS[j] =
            __builtin_amdgcn_mfma_f32_16x16x32_bf16(qreg[ks], bv, accS[j], 0, 0, 0);
      }
    }
    __builtin_amdgcn_s_setprio(0);

    // ---- online softmax (rows = hi*4 + r), defer-max past THR ----
#pragma unroll
    for (int j = 0; j < 2; ++j)
#pragma unroll
      for (int r = 0; r < 4; ++r) accS[j][r] *= scale;

    float tm[4];
#pragma unroll
    for (int r = 0; r < 4; ++r) {
      float tv = fmaxf(accS[0][r], accS[1][r]);
#pragma unroll
      for (int off = 1; off < 16; off <<= 1) tv = fmaxf(tv, __shfl_xor(tv, off, 64));
      tm[r] = tv;
    }
    const bool grow = (tm[0] > m[0] + THR) | (tm[1] > m[1] + THR) |
                      (tm[2] > m[2] + THR) | (tm[3] > m[3] + THR);
    if (__any(grow)) {  // wave-uniform branch
      float resc[4];
#pragma unroll
      for (int r = 0; r < 4; ++r) {
        const float mn = fmaxf(m[r], tm[r]);
        resc[r] = __expf(m[r] - mn);
        m[r] = mn;
        l[r] *= resc[r];
      }
#pragma unroll
      for (int n = 0; n < 20; ++n)
#pragma unroll
        for (int r = 0; r < 4; ++r) accO[n][r] *= resc[r];
    }
#pragma unroll
    for (int r = 0; r < 4; ++r) {
      float ps = 0.f;
#pragma unroll
      for (int j = 0; j < 2; ++j) {
        const float p = __expf(accS[j][r] - m[r]);
        accS[j][r] = p;  // reuse as P
        ps += p;
      }
#pragma unroll
      for (int off = 1; off < 16; off <<= 1) ps += __shfl_xor(ps, off, 64);
      l[r] += ps;
    }

    // ---- P (acc layout) -> per-wave LDS tile -> A-fragments ----
#pragma unroll
    for (int j = 0; j < 2; ++j)
#pragma unroll
      for (int r = 0; r < 4; ++r)
        plds[wave][hi * 4 + r][j * 16 + lr] = f2b(accS[j][r]);
    // intra-wave RAW through LDS: same-lane alias forces ordering; per-wave
    // private tile — no barrier needed.

    // ---- O += P @ V (single k=32 slice) ----
    {
      const bf16x8 pa = *reinterpret_cast<const bf16x8*>(&plds[wave][lr][hi * 8]);
      __builtin_amdgcn_s_setprio(1);
#pragma unroll
      for (int n = 0; n < 20; ++n) {
        const bf16x8 bv =
            *reinterpret_cast<const bf16x8*>(&Vts[n * 16 + lr][hi * 8]);
        accO[n] = __builtin_amdgcn_mfma_f32_16x16x32_bf16(pa, bv, accO[n], 0, 0, 0);
      }
      __builtin_amdgcn_s_setprio(0);
    }
  }

  // ---- write unnormalized partials ----
  const long long obase = (((long long)(s * Bb + b)) * Nn + qrow) * Cc;
#pragma unroll
  for (int n = 0; n < 20; ++n)
#pragma unroll
    for (int r = 0; r < 4; ++r)
      pO[obase + (long long)(hi * 4 + r) * Cc + n * 16 + lr] = accO[n][r];
  if (lr == 0) {
#pragma unroll
    for (int r = 0; r < 4; ++r) {
      const long long mlb =
          (((long long)(s * Bb + b)) * Nn + qrow + hi * 4 + r) * 2;
      pml[mlb] = m[r];
      pml[mlb + 1] = l[r];
    }
  }
}

// ---------------- combine kv-split partials -> ob (bf16) --------------------
__global__ __launch_bounds__(256) void fcomb(const float* __restrict__ pO,
                                             const float* __restrict__ pml,
                                             u16* __restrict__ ob) {
  const int row = blockIdx.x * 8 + (threadIdx.x >> 5);  // 0..8191
  const int lane32 = threadIdx.x & 31;
  const int b = row >> 12, rb = row & 4095;
  float ms[KVS], ls[KVS], mm = -INFINITY;
#pragma unroll
  for (int s = 0; s < KVS; ++s) {
    const long long i = (((long long)(s * Bb + b)) * Nn + rb) * 2;
    ms[s] = pml[i];
    ls[s] = pml[i + 1];
    mm = fmaxf(mm, ms[s]);
  }
  float w[KVS], den = 0.f;
#pragma unroll
  for (int s = 0; s < KVS; ++s) {
    w[s] = __expf(ms[s] - mm);
    den += w[s] * ls[s];
  }
  const float inv = 1.0f / den;
#pragma unroll
  for (int kk = 0; kk < 3; ++kk) {
    const int c = kk * 128 + lane32 * 4;
    if (c < Cc) {
      float4 o = {0.f, 0.f, 0.f, 0.f};
#pragma unroll
      for (int s = 0; s < KVS; ++s) {
        const float4 v = *reinterpret_cast<const float4*>(
            pO + (((long long)(s * Bb + b)) * Nn + rb) * Cc + c);
        o.x += w[s] * v.x;
        o.y += w[s] * v.y;
        o.z += w[s] * v.z;
        o.w += w[s] * v.w;
      }
      ushort4 u;
      u.x = f2b(o.x * inv);
      u.y = f2b(o.y * inv);
      u.z = f2b(o.z * inv);
      u.w = f2b(o.w * inv);
      *reinterpret_cast<ushort4*>(ob + (long long)row * Cc + c) = u;
    }
  }
}

// ---------------- fp32 -> bf16 flat cast ------------------------------------
__global__ __launch_bounds__(256) void cast_b(const float* __restrict__ in,
                                              u16* __restrict__ out) {
  const size_t i = ((size_t)blockIdx.x * 256 + threadIdx.x) * 4;
  const float4 v = *reinterpret_cast<const float4*>(in + i);
  ushort4 o;
  o.x = f2b(v.x); o.y = f2b(v.y); o.z = f2b(v.z); o.w = f2b(v.w);
  *reinterpret_cast<ushort4*>(out + i) = o;
}

// ---------------- fp32 [R][C] -> bf16 [C][R] tiled transpose ----------------
__global__ __launch_bounds__(256) void tran_f2b(const float* __restrict__ in,
                                                u16* __restrict__ out, int R,
                                                int C) {
  __shared__ u16 t[32][33];
  const int c0 = blockIdx.x * 32, r0 = blockIdx.y * 32;
  const int tx = threadIdx.x, ty = threadIdx.y;  // 32 x 8
#pragma unroll
  for (int i = 0; i < 32; i += 8)
    t[ty + i][tx] = f2b(in[(size_t)(r0 + ty + i) * C + c0 + tx]);
  __syncthreads();
#pragma unroll
  for (int i = 0; i < 32; i += 8)
    out[(size_t)(c0 + ty + i) * R + r0 + tx] = t[tx][ty + i];
}

// ---------------- 8x [320][320] weight transposes in one dispatch -----------
struct P8 { const float* p[8]; };
__global__ __launch_bounds__(256) void tran8(P8 ps, u16* __restrict__ outall) {
  const float* in = ps.p[blockIdx.z];
  u16* out = outall + (size_t)blockIdx.z * 320 * 320;
  __shared__ u16 t[32][33];
  const int c0 = blockIdx.x * 32, r0 = blockIdx.y * 32;
  const int tx = threadIdx.x, ty = threadIdx.y;  // 32 x 8
#pragma unroll
  for (int i = 0; i < 32; i += 8)
    t[ty + i][tx] = f2b(in[(size_t)(r0 + ty + i) * 320 + c0 + tx]);
  __syncthreads();
#pragma unroll
  for (int i = 0; i < 32; i += 8)
    out[(size_t)(c0 + ty + i) * 320 + r0 + tx] = t[tx][ty + i];
}

// ---------------- concat biases: [sa_q|sa_k|sa_v|ca_k|ca_v] -----------------
__global__ __launch_bounds__(256) void prep_bias(
    const float* a, const float* b, const float* c, const float* d,
    const float* e, float* __restrict__ o) {
  const int i = blockIdx.x * 256 + threadIdx.x;
  if (i < 320) o[i] = a[i];
  else if (i < 640) o[i] = b[i - 320];
  else if (i < 960) o[i] = c[i - 640];
  else if (i < 1280) o[i] = d[i - 960];
  else if (i < 1600) o[i] = e[i - 1280];
}

// ---------------- GroupNorm ------------------------------------------------
__global__ __launch_bounds__(256) void gn_stats(const float* __restrict__ x,
                                                float* __restrict__ partials) {
  const int s = blockIdx.x % GN_SPLIT;
  const int bg = blockIdx.x / GN_SPLIT;
  const int b = bg / GROUPS, g = bg % GROUPS;
  const int rows = Nn / GN_SPLIT;  // 512
  const float* base = x + (size_t)b * Nn * Cc + g * CG;
  float sum = 0.f, sq = 0.f;
  for (int i = threadIdx.x; i < rows * CG; i += 256) {
    const int r = i / CG, c = i % CG;
    const float v = base[(size_t)(s * rows + r) * Cc + c];
    sum += v; sq += v * v;
  }
#pragma unroll
  for (int off = 32; off >= 1; off >>= 1) {
    sum += __shfl_xor(sum, off, 64);
    sq += __shfl_xor(sq, off, 64);
  }
  __shared__ float rs[4], rq[4];
  const int tid = threadIdx.x;
  if ((tid & 63) == 0) { rs[tid >> 6] = sum; rq[tid >> 6] = sq; }
  __syncthreads();
  if (tid == 0) {
    partials[(bg * GN_SPLIT + s) * 2 + 0] = rs[0] + rs[1] + rs[2] + rs[3];
    partials[(bg * GN_SPLIT + s) * 2 + 1] = rq[0] + rq[1] + rq[2] + rq[3];
  }
}

__global__ __launch_bounds__(256) void gn_apply(
    const float* __restrict__ x, const float* __restrict__ partials,
    const float* __restrict__ gamma, const float* __restrict__ beta,
    float* __restrict__ xn, u16* __restrict__ xnb) {
  const size_t idx = (size_t)blockIdx.x * 256 + threadIdx.x;
  const int c = (int)(idx % Cc);
  const size_t row = idx / Cc;
  const int b = (int)(row / Nn);
  const int bg = b * GROUPS + c / CG;
  float sum = 0.f, sq = 0.f;
#pragma unroll
  for (int s = 0; s < GN_SPLIT; ++s) {
    sum += partials[(bg * GN_SPLIT + s) * 2 + 0];
    sq += partials[(bg * GN_SPLIT + s) * 2 + 1];
  }
  const float cnt = (float)Nn * CG;
  const float mean = sum / cnt;
  const float var = sq / cnt - mean * mean;
  const float r = rsqrtf(var + EPS);
  const float v = (x[idx] - mean) * r * gamma[c] + beta[c];
  xn[idx] = v;
  xnb[idx] = f2b(v);
}

// ---------------- GEGLU combine: ff = xp[:, :1280] * qgelu(xp[:, 1280:]) ----
__global__ __launch_bounds__(256) void geglu_comb(const u16* __restrict__ xp,
                                                  u16* __restrict__ ff) {
  const size_t i = ((size_t)blockIdx.x * 256 + threadIdx.x) * 4;  // over M*1280
  const size_t row = i / 1280, c = i % 1280;
  const u16* p = xp + row * 2560;
  const ushort4 a = *reinterpret_cast<const ushort4*>(p + c);
  const ushort4 b = *reinterpret_cast<const ushort4*>(p + 1280 + c);
  ushort4 o;
  float v1, v2;
  v1 = b2f(a.x); v2 = b2f(b.x);
  o.x = f2b(v1 * (v2 / (1.0f + __expf(-1.702f * v2))));
  v1 = b2f(a.y); v2 = b2f(b.y);
  o.y = f2b(v1 * (v2 / (1.0f + __expf(-1.702f * v2))));
  v1 = b2f(a.z); v2 = b2f(b.z);
  o.z = f2b(v1 * (v2 / (1.0f + __expf(-1.702f * v2))));
  v1 = b2f(a.w); v2 = b2f(b.w);
  o.w = f2b(v1 * (v2 / (1.0f + __expf(-1.702f * v2))));
  *reinterpret_cast<ushort4*>(ff + i) = o;
}

// ---------------------------------------------------------------------------
extern "C" void kernel_launch(void* const* d_in, const int* in_sizes, int n_in,
                              void* d_out, int out_size, void* d_ws,
                              size_t ws_size, hipStream_t stream) {
  const float* x   = (const float*)d_in[0];
  const float* ctx = (const float*)d_in[1];
  const float* W[8];
  const float* Bv[8];
  for (int i = 0; i < 8; ++i) {
    W[i]  = (const float*)d_in[2 + 2 * i];
    Bv[i] = (const float*)d_in[3 + 2 * i];
  }
  const float* gn_g = (const float*)d_in[18];
  const float* gn_b = (const float*)d_in[19];
  const float* gw   = (const float*)d_in[20];
  const float* gb   = (const float*)d_in[21];
  const float* dw   = (const float*)d_in[22];
  const float* db   = (const float*)d_in[23];
  float* out = (float*)d_out;

  // ---- workspace layout (bytes, 256-aligned) ----
  char* base = (char*)d_ws;
  size_t o = 0;
  auto alloc = [&](size_t bytes) {
    void* p = base + o;
    o = (o + bytes + 255) & ~(size_t)255;
    return p;
  };
  u16* wTall = (u16*)alloc((size_t)8 * 320 * 320 * 2);  // contiguous 8 weights
  u16* gwT  = (u16*)alloc((size_t)2560 * 320 * 2);
  u16* dwT  = (u16*)alloc((size_t)320 * 1280 * 2);
  u16* xb   = (u16*)alloc((size_t)Mm * Cc * 2);
  u16* ctxb = (u16*)alloc((size_t)Mm * Cc * 2);
  float* x2 = (float*)alloc((size_t)Mm * Cc * 4);
  float* xn = (float*)alloc((size_t)Mm * Cc * 4);
  u16* xnb  = (u16*)alloc((size_t)Mm * Cc * 2);
  float* x3 = (float*)alloc((size_t)Mm * Cc * 4);
  u16* x3b  = (u16*)alloc((size_t)Mm * Cc * 2);
  float* biasCat = (float*)alloc(1600 * 4);
  float* stats = (float*)alloc(4096);
  // attention scratch; xp aliases the pO region (distinct phases)
  const size_t FIXED = 26214400;  // qkb 10.49M + kb/vtb/ob 5.24M each
  const size_t POSZ = (size_t)KVS * Bb * Nn * Cc * 4;  // 41.94 MB
  const size_t SCRSZ = FIXED + POSZ + 524288;
  char* SCR = (char*)alloc(SCRSZ);
  u16* qkb = (u16*)SCR;                  // [M][640] (self qkv) / [M][320] (cross q)
  u16* kb  = (u16*)(SCR + 10485760);     // [M][320]
  u16* vtb = (u16*)(SCR + 15728640);     // [b][Cc][Nn]
  u16* ob  = (u16*)(SCR + 20971520);     // [M][Cc]
  char* REST = SCR + FIXED;
  float* pO  = (float*)REST;                     // flash partials
  float* pml = (float*)(REST + POSZ);            // 256 KB
  u16* xp = (u16*)REST;                          // [M][2560] (FFN phase)
  u16* ffb = (u16*)x2;  // [M][1280] aliases x2+xn (both dead by FFN phase)

  if (base == nullptr || ws_size < o) return;  // d_out stays poisoned

  const float scale = 1.0f / sqrtf((float)Cc);
  u16* wT[8];
  for (int i = 0; i < 8; ++i) wT[i] = wTall + (size_t)i * 320 * 320;

  // ---- prep: casts, weight transposes, bias concat ----
  cast_b<<<(Mm * Cc) / 1024, 256, 0, stream>>>(x, xb);
  cast_b<<<(Mm * Cc) / 1024, 256, 0, stream>>>(ctx, ctxb);
  {
    P8 ps;
    for (int i = 0; i < 8; ++i) ps.p[i] = W[i];
    tran8<<<dim3(10, 10, 8), dim3(32, 8), 0, stream>>>(ps, wTall);
  }
  tran_f2b<<<dim3(80, 10), dim3(32, 8), 0, stream>>>(gw, gwT, 320, 2560);
  tran_f2b<<<dim3(10, 40), dim3(32, 8), 0, stream>>>(dw, dwT, 1280, 320);
  prep_bias<<<7, 256, 0, stream>>>(Bv[0], Bv[1], Bv[2], Bv[5], Bv[6], biasCat);

  // ---- self-attention ----
  // fused q|k|v projection: N=960, B = [wq;wk;wv] (wTall contiguous),
  // cols<640 -> qkb [M][640]; cols>=640 -> vtb transposed
  gemm_nt<false, false, true><<<dim3(15, 64, 1), 256, 0, stream>>>(
      xb, Cc, 0, wT[0], Cc, 0, biasCat, nullptr, 0.f, nullptr, qkb, 640, 0,
      nullptr, vtb, 640, Cc, 1.f);
  flash_k<<<dim3(Nn / 64, KVS, Bb), 256, 0, stream>>>(qkb, 640, qkb + 320, 640,
                                                      vtb, pO, pml, scale);
  fcomb<<<Mm / 8, 256, 0, stream>>>(pO, pml, ob);
  // x2 = o@Wp + bp + 2*x
  gemm_nt<true, false, false><<<dim3(5, 64, 1), 256, 0, stream>>>(
      ob, Cc, 0, wT[3], Cc, 0, Bv[3], x, 2.0f, nullptr, x2, Cc, 0, nullptr,
      nullptr, 0, Cc, 1.f);

  // ---- GroupNorm(x2) -> xn (fp32) + xnb (bf16) ----
  gn_stats<<<Bb * GROUPS * GN_SPLIT, 256, 0, stream>>>(x2, stats);
  gn_apply<<<(Mm * Cc) / 256, 256, 0, stream>>>(x2, stats, gn_g, gn_b, xn, xnb);

  // ---- cross-attention ----
  // q projection from xnb (N=320)
  gemm_nt<false, false, false><<<dim3(5, 64, 1), 256, 0, stream>>>(
      xnb, Cc, 0, wT[4], Cc, 0, Bv[4], nullptr, 0.f, nullptr, qkb, 320, 0,
      nullptr, nullptr, 0, Cc, 1.f);
  // fused k|v projection from ctxb: N=640, cols<320 -> kb; cols>=320 -> vtb
  gemm_nt<false, false, true><<<dim3(10, 64, 1), 256, 0, stream>>>(
      ctxb, Cc, 0, wT[5], Cc, 0, biasCat + 960, nullptr, 0.f, nullptr, kb, 320,
      0, nullptr, vtb, 320, Cc, 1.f);
  flash_k<<<dim3(Nn / 64, KVS, Bb), 256, 0, stream>>>(qkb, 320, kb, 320, vtb,
                                                      pO, pml, scale);
  fcomb<<<Mm / 8, 256, 0, stream>>>(pO, pml, ob);
  // x3 = o@Wp2 + bp2 + xn + x2 (fp32 + bf16 dual)
  gemm_nt<true, true, false><<<dim3(5, 64, 1), 256, 0, stream>>>(
      ob, Cc, 0, wT[7], Cc, 0, Bv[7], xn, 1.0f, x2, x3, Cc, 0, x3b, nullptr, 0,
      Cc, 1.f);

  // ---- GEGLU FFN: fused N=2560 gemm -> xp; comb -> ffb; dense -> out ----
  gemm_nt<false, false, false><<<dim3(40, 64, 1), 256, 0, stream>>>(
      x3b, Cc, 0, gwT, Cc, 0, gb, nullptr, 0.f, nullptr, xp, 2560, 0, nullptr,
      nullptr, 0, Cc, 1.f);
  geglu_comb<<<(int)(((size_t)Mm * 1280) / 1024), 256, 0, stream>>>(xp, ffb);
  gemm_nt<true, false, false><<<dim3(5, 64, 1), 256, 0, stream>>>(
      ffb, 1280, 0, dwT, 1280, 0, db, x3, 1.0f, nullptr, out, Cc, 0, nullptr,
      nullptr, 0, 1280, 1.f);
}

// Round 10
// 519.713 us; speedup vs baseline: 1.7490x; 1.0617x over previous
//
#include <hip/hip_runtime.h>
#include <math.h>
#include <stdint.h>

// ---------------------------------------------------------------------------
// BasicTransformerBlock (B=2, H=W=64, C=320) — bf16 MFMA, fused projections,
// prefetched GEMMs (T14), LDS-staged prefetched flash attention.
// x2 = 2x + selfattn(x);  xn = GN(x2);  x3 = xn + crossattn(xn,ctx) + x2
// ff = geglu(x3);  out = ff @ Wd + bd + x3
// ---------------------------------------------------------------------------

typedef unsigned short u16;
typedef __attribute__((ext_vector_type(8))) short bf16x8;
typedef __attribute__((ext_vector_type(8))) unsigned short u16x8;
typedef __attribute__((ext_vector_type(4))) float f32x4;

constexpr int Bb = 2, Cc = 320;
constexpr int Nn = 64 * 64;                    // 4096 tokens per batch
constexpr int Mm = Bb * Nn;                    // 8192 rows
constexpr int GROUPS = 16, CG = Cc / GROUPS;   // 20
constexpr float EPS = 1e-3f;
constexpr int GN_SPLIT = 8;
constexpr int KVS = 4;                         // kv splits (flash)
constexpr int KVC = Nn / KVS;                  // 1024 kv rows per block
constexpr int KVT = 32;                        // kv rows per LDS tile
constexpr float THR = 8.f;                     // defer-max threshold (T13)

__device__ __forceinline__ u16 f2b(float f) {
  unsigned u = __float_as_uint(f);
  unsigned r = u + 0x7fffu + ((u >> 16) & 1u);
  return (u16)(r >> 16);
}
__device__ __forceinline__ float b2f(u16 h) {
  return __uint_as_float(((unsigned)h) << 16);
}

// ---------------- bf16 NT GEMM, prefetched, fused epilogue ------------------
// C = scale*(A@B^T) + bias + alpha1*R1 + R2 ; C fp32 (F32OUT) or bf16.
// DUAL: extra bf16 copy to C2. VTS: cols >= vtc0 written TRANSPOSED bf16 into
// VT as [b][c][row%Nn]. BM=128: 4 waves x (64x32); BM=64: 4 waves x (32x32).
// T14: next K-step's global loads issue right after barrier B.
template <int BM, bool F32OUT, bool DUAL, bool VTS>
__global__ __launch_bounds__(256) void gemm_nt(
    const u16* __restrict__ A, int lda, long long aZ,
    const u16* __restrict__ B, int ldb, long long bZ,
    const float* __restrict__ bias,
    const float* __restrict__ R1, float alpha1,
    const float* __restrict__ R2,
    void* __restrict__ Cp, int ldc, long long cZ,
    u16* __restrict__ C2,
    u16* __restrict__ VT, int vtc0,
    int K, float scale) {
  constexpr int IM = BM / 32;  // 4 or 2 row-frags per wave
  const int z = blockIdx.z;
  A += (long long)z * aZ;
  B += (long long)z * bZ;
  const long long coffz = (long long)z * cZ;

  __shared__ __align__(16) u16 As[BM][40];  // +8 pad: conflict-free reads
  __shared__ __align__(16) u16 Bs[64][40];

  const int tid = threadIdx.x;
  const int bm = blockIdx.y * BM, bn = blockIdx.x * 64;
  const int lane = tid & 63;
  const int wid = tid >> 6;
  const int wm = (wid >> 1) * (BM / 2), wn = (wid & 1) * 32;
  const int lr = lane & 15, lk = (lane >> 4) * 8;  // frag row, k-off

  const int sr = tid >> 2;        // staging row 0..63
  const int sk = (tid & 3) * 8;   // staging k offset

  f32x4 acc[IM][2] = {};

  const u16* Ap0 = A + (size_t)(bm + sr) * lda + sk;
  const u16* Ap1 = A + (size_t)(bm + 64 + sr) * lda + sk;  // BM=128 only
  const u16* Bp0 = B + (size_t)(bn + sr) * ldb + sk;

  u16x8 a0, a1, b0;  // prefetch regs (T14)
  auto issue = [&](int k0) {
    a0 = *reinterpret_cast<const u16x8*>(Ap0 + k0);
    if (BM == 128) a1 = *reinterpret_cast<const u16x8*>(Ap1 + k0);
    b0 = *reinterpret_cast<const u16x8*>(Bp0 + k0);
  };

  issue(0);
  for (int k0 = 0; k0 < K; k0 += 32) {
    *reinterpret_cast<u16x8*>(&As[sr][sk]) = a0;
    if (BM == 128) *reinterpret_cast<u16x8*>(&As[64 + sr][sk]) = a1;
    *reinterpret_cast<u16x8*>(&Bs[sr][sk]) = b0;
    __syncthreads();

    if (k0 + 32 < K) issue(k0 + 32);  // latency hides under MFMA below

    bf16x8 af[IM], bfr[2];
#pragma unroll
    for (int i = 0; i < IM; ++i)
      af[i] = *reinterpret_cast<const bf16x8*>(&As[wm + i * 16 + lr][lk]);
#pragma unroll
    for (int j = 0; j < 2; ++j)
      bfr[j] = *reinterpret_cast<const bf16x8*>(&Bs[wn + j * 16 + lr][lk]);
#pragma unroll
    for (int i = 0; i < IM; ++i)
#pragma unroll
      for (int j = 0; j < 2; ++j)
        acc[i][j] = __builtin_amdgcn_mfma_f32_16x16x32_bf16(af[i], bfr[j],
                                                            acc[i][j], 0, 0, 0);
    __syncthreads();
  }

  float* Cf = (float*)Cp;
  u16* Cb = (u16*)Cp;
#pragma unroll
  for (int i = 0; i < IM; ++i)
#pragma unroll
    for (int j = 0; j < 2; ++j) {
      // verified C/D layout: col = lane&15, row = (lane>>4)*4 + reg
      const int col = bn + wn + j * 16 + lr;
      const int row0 = bm + wm + i * 16 + (lane >> 4) * 4;
      if (VTS && col >= vtc0) {
        const int c = col - vtc0;
        const int bz = row0 >> 12, rb = row0 & 4095;
        ushort4 u;
        u.x = f2b(acc[i][j][0] * scale + bias[col]);
        u.y = f2b(acc[i][j][1] * scale + bias[col]);
        u.z = f2b(acc[i][j][2] * scale + bias[col]);
        u.w = f2b(acc[i][j][3] * scale + bias[col]);
        *reinterpret_cast<ushort4*>(VT + ((long long)bz * Cc + c) * Nn + rb) = u;
      } else {
#pragma unroll
        for (int r = 0; r < 4; ++r) {
          const long long off = (long long)(row0 + r) * ldc + col + coffz;
          float v = acc[i][j][r] * scale;
          if (bias) v += bias[col];
          if (R1) v += alpha1 * R1[off];
          if (R2) v += R2[off];
          if (F32OUT) Cf[off] = v; else Cb[off] = f2b(v);
          if (DUAL) C2[off] = f2b(v);
        }
      }
    }
}

// ---------------- fused flash attention (LDS-staged, prefetched) ------------
// Per block: 64 q-rows (4 waves x 16 rows), kv chunk KVC, KVT-row LDS tiles.
// T14: tile t+1's global loads issue right after barrier B. Defer-max (THR)
// skips accO rescale unless tile max grows past m+THR. launch_bounds(256,2):
// R7's ,3 spilled (VGPR 84, 2.3x hbm traffic).
__global__ __launch_bounds__(256, 2) void flash_k(
    const u16* __restrict__ q, int qlda, const u16* __restrict__ k, int klda,
    const u16* __restrict__ vtb, float* __restrict__ pO,
    float* __restrict__ pml, float scale) {
  const int qt = blockIdx.x, s = blockIdx.y, b = blockIdx.z;
  const int tid = threadIdx.x, wave = tid >> 6, lane = tid & 63;
  const int lr = lane & 15, hi = lane >> 4;
  const int qrow = qt * 64 + wave * 16;  // within batch

  // LDS: 21504 + 25600 + 5120 = 52224 B
  __shared__ __align__(16) u16 Ks[KVT][336];
  __shared__ __align__(16) u16 Vts[Cc][40];
  __shared__ __align__(16) u16 plds[4][16][40];

  // Q strip 16x320 in registers (A-fragments)
  bf16x8 qreg[10];
  const long long qbase = ((long long)b * Nn + qrow + lr) * qlda;
#pragma unroll
  for (int ks = 0; ks < 10; ++ks)
    qreg[ks] = *reinterpret_cast<const bf16x8*>(q + qbase + ks * 32 + hi * 8);

  f32x4 accO[20] = {};
  float m[4] = {-INFINITY, -INFINITY, -INFINITY, -INFINITY};
  float l[4] = {0.f, 0.f, 0.f, 0.f};

  const u16* kbb = k + (long long)b * Nn * klda;
  const u16* vtbb = vtb + (long long)b * Cc * Nn;
  const int kv0 = s * KVC;

  const int krow = tid >> 3;  // 0..31 (K staging row)
  const int kcb = tid & 7;    // K staging 16B-chunk base
  u16x8 kst[5], vst[5];       // staging regs, live across compute (T14)

  auto issue = [&](int t) {
    const int kvb = kv0 + t * KVT;
#pragma unroll
    for (int c = 0; c < 5; ++c)
      kst[c] = *reinterpret_cast<const u16x8*>(
          kbb + (long long)(kvb + krow) * klda + (kcb + 8 * c) * 8);
#pragma unroll
    for (int c = 0; c < 5; ++c) {
      const int id = tid + 256 * c;  // 0..1279
      const int vr = id >> 2, vc = id & 3;
      vst[c] = *reinterpret_cast<const u16x8*>(
          vtbb + (long long)vr * Nn + kvb + vc * 8);
    }
  };

  issue(0);
  constexpr int NT = KVC / KVT;  // 32
  for (int t = 0; t < NT; ++t) {
    __syncthreads();  // A: all waves done reading LDS tile t-1
#pragma unroll
    for (int c = 0; c < 5; ++c)
      *reinterpret_cast<u16x8*>(&Ks[krow][(kcb + 8 * c) * 8]) = kst[c];
#pragma unroll
    for (int c = 0; c < 5; ++c) {
      const int id = tid + 256 * c;
      const int vr = id >> 2, vc = id & 3;
      *reinterpret_cast<u16x8*>(&Vts[vr][vc * 8]) = vst[c];
    }
    __syncthreads();  // B: tile visible to all waves

    if (t + 1 < NT) issue(t + 1);  // prefetch: latency hides under compute

    // ---- S = Q @ K^T for 16x32 strip ----
    f32x4 accS[2] = {};
    __builtin_amdgcn_s_setprio(1);
#pragma unroll
    for (int ks = 0; ks < 10; ++ks) {
#pragma unroll
      for (int j = 0; j < 2; ++j) {
        const bf16x8 bv =
            *reinterpret_cast<const bf16x8*>(&Ks[j * 16 + lr][ks * 32 + hi * 8]);
        accS[j] =
            __builtin_amdgcn_mfma_f32_16x16x32_bf16(qreg[ks], bv, accS[j], 0, 0, 0);
      }
    }
    __builtin_amdgcn_s_setprio(0);

    // ---- online softmax (rows = hi*4 + r), defer-max past THR ----
#pragma unroll
    for (int j = 0; j < 2; ++j)
#pragma unroll
      for (int r = 0; r < 4; ++r) accS[j][r] *= scale;

    float tm[4];
#pragma unroll
    for (int r = 0; r < 4; ++r) {
      float tv = fmaxf(accS[0][r], accS[1][r]);
#pragma unroll
      for (int off = 1; off < 16; off <<= 1) tv = fmaxf(tv, __shfl_xor(tv, off, 64));
      tm[r] = tv;
    }
    const bool grow = (tm[0] > m[0] + THR) | (tm[1] > m[1] + THR) |
                      (tm[2] > m[2] + THR) | (tm[3] > m[3] + THR);
    if (__any(grow)) {  // wave-uniform branch
      float resc[4];
#pragma unroll
      for (int r = 0; r < 4; ++r) {
        const float mn = fmaxf(m[r], tm[r]);
        resc[r] = __expf(m[r] - mn);
        m[r] = mn;
        l[r] *= resc[r];
      }
#pragma unroll
      for (int n = 0; n < 20; ++n)
#pragma unroll
        for (int r = 0; r < 4; ++r) accO[n][r] *= resc[r];
    }
#pragma unroll
    for (int r = 0; r < 4; ++r) {
      float ps = 0.f;
#pragma unroll
      for (int j = 0; j < 2; ++j) {
        const float p = __expf(accS[j][r] - m[r]);
        accS[j][r] = p;  // reuse as P
        ps += p;
      }
#pragma unroll
      for (int off = 1; off < 16; off <<= 1) ps += __shfl_xor(ps, off, 64);
      l[r] += ps;
    }

    // ---- P (acc layout) -> per-wave LDS tile -> A-fragments ----
#pragma unroll
    for (int j = 0; j < 2; ++j)
#pragma unroll
      for (int r = 0; r < 4; ++r)
        plds[wave][hi * 4 + r][j * 16 + lr] = f2b(accS[j][r]);
    // intra-wave RAW through LDS: same-lane alias forces ordering; per-wave
    // private tile — no barrier needed.

    // ---- O += P @ V (single k=32 slice) ----
    {
      const bf16x8 pa = *reinterpret_cast<const bf16x8*>(&plds[wave][lr][hi * 8]);
      __builtin_amdgcn_s_setprio(1);
#pragma unroll
      for (int n = 0; n < 20; ++n) {
        const bf16x8 bv =
            *reinterpret_cast<const bf16x8*>(&Vts[n * 16 + lr][hi * 8]);
        accO[n] = __builtin_amdgcn_mfma_f32_16x16x32_bf16(pa, bv, accO[n], 0, 0, 0);
      }
      __builtin_amdgcn_s_setprio(0);
    }
  }

  // ---- write unnormalized partials ----
  const long long obase = (((long long)(s * Bb + b)) * Nn + qrow) * Cc;
#pragma unroll
  for (int n = 0; n < 20; ++n)
#pragma unroll
    for (int r = 0; r < 4; ++r)
      pO[obase + (long long)(hi * 4 + r) * Cc + n * 16 + lr] = accO[n][r];
  if (lr == 0) {
#pragma unroll
    for (int r = 0; r < 4; ++r) {
      const long long mlb =
          (((long long)(s * Bb + b)) * Nn + qrow + hi * 4 + r) * 2;
      pml[mlb] = m[r];
      pml[mlb + 1] = l[r];
    }
  }
}

// ---------------- combine kv-split partials -> ob (bf16) --------------------
__global__ __launch_bounds__(256) void fcomb(const float* __restrict__ pO,
                                             const float* __restrict__ pml,
                                             u16* __restrict__ ob) {
  const int row = blockIdx.x * 8 + (threadIdx.x >> 5);  // 0..8191
  const int lane32 = threadIdx.x & 31;
  const int b = row >> 12, rb = row & 4095;
  float ms[KVS], ls[KVS], mm = -INFINITY;
#pragma unroll
  for (int s = 0; s < KVS; ++s) {
    const long long i = (((long long)(s * Bb + b)) * Nn + rb) * 2;
    ms[s] = pml[i];
    ls[s] = pml[i + 1];
    mm = fmaxf(mm, ms[s]);
  }
  float w[KVS], den = 0.f;
#pragma unroll
  for (int s = 0; s < KVS; ++s) {
    w[s] = __expf(ms[s] - mm);
    den += w[s] * ls[s];
  }
  const float inv = 1.0f / den;
#pragma unroll
  for (int kk = 0; kk < 3; ++kk) {
    const int c = kk * 128 + lane32 * 4;
    if (c < Cc) {
      float4 o = {0.f, 0.f, 0.f, 0.f};
#pragma unroll
      for (int s = 0; s < KVS; ++s) {
        const float4 v = *reinterpret_cast<const float4*>(
            pO + (((long long)(s * Bb + b)) * Nn + rb) * Cc + c);
        o.x += w[s] * v.x;
        o.y += w[s] * v.y;
        o.z += w[s] * v.z;
        o.w += w[s] * v.w;
      }
      ushort4 u;
      u.x = f2b(o.x * inv);
      u.y = f2b(o.y * inv);
      u.z = f2b(o.z * inv);
      u.w = f2b(o.w * inv);
      *reinterpret_cast<ushort4*>(ob + (long long)row * Cc + c) = u;
    }
  }
}

// ---------------- fp32 -> bf16 flat cast ------------------------------------
__global__ __launch_bounds__(256) void cast_b(const float* __restrict__ in,
                                              u16* __restrict__ out) {
  const size_t i = ((size_t)blockIdx.x * 256 + threadIdx.x) * 4;
  const float4 v = *reinterpret_cast<const float4*>(in + i);
  ushort4 o;
  o.x = f2b(v.x); o.y = f2b(v.y); o.z = f2b(v.z); o.w = f2b(v.w);
  *reinterpret_cast<ushort4*>(out + i) = o;
}

// ---------------- fp32 [R][C] -> bf16 [C][R] tiled transpose ----------------
__global__ __launch_bounds__(256) void tran_f2b(const float* __restrict__ in,
                                                u16* __restrict__ out, int R,
                                                int C) {
  __shared__ u16 t[32][33];
  const int c0 = blockIdx.x * 32, r0 = blockIdx.y * 32;
  const int tx = threadIdx.x, ty = threadIdx.y;  // 32 x 8
#pragma unroll
  for (int i = 0; i < 32; i += 8)
    t[ty + i][tx] = f2b(in[(size_t)(r0 + ty + i) * C + c0 + tx]);
  __syncthreads();
#pragma unroll
  for (int i = 0; i < 32; i += 8)
    out[(size_t)(c0 + ty + i) * R + r0 + tx] = t[tx][ty + i];
}

// ---------------- 8x [320][320] weight transposes in one dispatch -----------
struct P8 { const float* p[8]; };
__global__ __launch_bounds__(256) void tran8(P8 ps, u16* __restrict__ outall) {
  const float* in = ps.p[blockIdx.z];
  u16* out = outall + (size_t)blockIdx.z * 320 * 320;
  __shared__ u16 t[32][33];
  const int c0 = blockIdx.x * 32, r0 = blockIdx.y * 32;
  const int tx = threadIdx.x, ty = threadIdx.y;  // 32 x 8
#pragma unroll
  for (int i = 0; i < 32; i += 8)
    t[ty + i][tx] = f2b(in[(size_t)(r0 + ty + i) * 320 + c0 + tx]);
  __syncthreads();
#pragma unroll
  for (int i = 0; i < 32; i += 8)
    out[(size_t)(c0 + ty + i) * 320 + r0 + tx] = t[tx][ty + i];
}

// ---------------- concat biases: [sa_q|sa_k|sa_v|ca_k|ca_v] -----------------
__global__ __launch_bounds__(256) void prep_bias(
    const float* a, const float* b, const float* c, const float* d,
    const float* e, float* __restrict__ o) {
  const int i = blockIdx.x * 256 + threadIdx.x;
  if (i < 320) o[i] = a[i];
  else if (i < 640) o[i] = b[i - 320];
  else if (i < 960) o[i] = c[i - 640];
  else if (i < 1280) o[i] = d[i - 960];
  else if (i < 1600) o[i] = e[i - 1280];
}

// ---------------- GroupNorm ------------------------------------------------
__global__ __launch_bounds__(256) void gn_stats(const float* __restrict__ x,
                                                float* __restrict__ partials) {
  const int s = blockIdx.x % GN_SPLIT;
  const int bg = blockIdx.x / GN_SPLIT;
  const int b = bg / GROUPS, g = bg % GROUPS;
  const int rows = Nn / GN_SPLIT;  // 512
  const float* base = x + (size_t)b * Nn * Cc + g * CG;
  float sum = 0.f, sq = 0.f;
  for (int i = threadIdx.x; i < rows * CG; i += 256) {
    const int r = i / CG, c = i % CG;
    const float v = base[(size_t)(s * rows + r) * Cc + c];
    sum += v; sq += v * v;
  }
#pragma unroll
  for (int off = 32; off >= 1; off >>= 1) {
    sum += __shfl_xor(sum, off, 64);
    sq += __shfl_xor(sq, off, 64);
  }
  __shared__ float rs[4], rq[4];
  const int tid = threadIdx.x;
  if ((tid & 63) == 0) { rs[tid >> 6] = sum; rq[tid >> 6] = sq; }
  __syncthreads();
  if (tid == 0) {
    partials[(bg * GN_SPLIT + s) * 2 + 0] = rs[0] + rs[1] + rs[2] + rs[3];
    partials[(bg * GN_SPLIT + s) * 2 + 1] = rq[0] + rq[1] + rq[2] + rq[3];
  }
}

__global__ __launch_bounds__(256) void gn_apply(
    const float* __restrict__ x, const float* __restrict__ partials,
    const float* __restrict__ gamma, const float* __restrict__ beta,
    float* __restrict__ xn, u16* __restrict__ xnb) {
  const size_t idx = (size_t)blockIdx.x * 256 + threadIdx.x;
  const int c = (int)(idx % Cc);
  const size_t row = idx / Cc;
  const int b = (int)(row / Nn);
  const int bg = b * GROUPS + c / CG;
  float sum = 0.f, sq = 0.f;
#pragma unroll
  for (int s = 0; s < GN_SPLIT; ++s) {
    sum += partials[(bg * GN_SPLIT + s) * 2 + 0];
    sq += partials[(bg * GN_SPLIT + s) * 2 + 1];
  }
  const float cnt = (float)Nn * CG;
  const float mean = sum / cnt;
  const float var = sq / cnt - mean * mean;
  const float r = rsqrtf(var + EPS);
  const float v = (x[idx] - mean) * r * gamma[c] + beta[c];
  xn[idx] = v;
  xnb[idx] = f2b(v);
}

// ---------------- GEGLU combine: ff = xp[:, :1280] * qgelu(xp[:, 1280:]) ----
__global__ __launch_bounds__(256) void geglu_comb(const u16* __restrict__ xp,
                                                  u16* __restrict__ ff) {
  const size_t i = ((size_t)blockIdx.x * 256 + threadIdx.x) * 4;  // over M*1280
  const size_t row = i / 1280, c = i % 1280;
  const u16* p = xp + row * 2560;
  const ushort4 a = *reinterpret_cast<const ushort4*>(p + c);
  const ushort4 b = *reinterpret_cast<const ushort4*>(p + 1280 + c);
  ushort4 o;
  float v1, v2;
  v1 = b2f(a.x); v2 = b2f(b.x);
  o.x = f2b(v1 * (v2 / (1.0f + __expf(-1.702f * v2))));
  v1 = b2f(a.y); v2 = b2f(b.y);
  o.y = f2b(v1 * (v2 / (1.0f + __expf(-1.702f * v2))));
  v1 = b2f(a.z); v2 = b2f(b.z);
  o.z = f2b(v1 * (v2 / (1.0f + __expf(-1.702f * v2))));
  v1 = b2f(a.w); v2 = b2f(b.w);
  o.w = f2b(v1 * (v2 / (1.0f + __expf(-1.702f * v2))));
  *reinterpret_cast<ushort4*>(ff + i) = o;
}

// ---------------------------------------------------------------------------
extern "C" void kernel_launch(void* const* d_in, const int* in_sizes, int n_in,
                              void* d_out, int out_size, void* d_ws,
                              size_t ws_size, hipStream_t stream) {
  const float* x   = (const float*)d_in[0];
  const float* ctx = (const float*)d_in[1];
  const float* W[8];
  const float* Bv[8];
  for (int i = 0; i < 8; ++i) {
    W[i]  = (const float*)d_in[2 + 2 * i];
    Bv[i] = (const float*)d_in[3 + 2 * i];
  }
  const float* gn_g = (const float*)d_in[18];
  const float* gn_b = (const float*)d_in[19];
  const float* gw   = (const float*)d_in[20];
  const float* gb   = (const float*)d_in[21];
  const float* dw   = (const float*)d_in[22];
  const float* db   = (const float*)d_in[23];
  float* out = (float*)d_out;

  // ---- workspace layout (bytes, 256-aligned) ----
  char* base = (char*)d_ws;
  size_t o = 0;
  auto alloc = [&](size_t bytes) {
    void* p = base + o;
    o = (o + bytes + 255) & ~(size_t)255;
    return p;
  };
  u16* wTall = (u16*)alloc((size_t)8 * 320 * 320 * 2);  // contiguous 8 weights
  u16* gwT  = (u16*)alloc((size_t)2560 * 320 * 2);
  u16* dwT  = (u16*)alloc((size_t)320 * 1280 * 2);
  u16* xb   = (u16*)alloc((size_t)Mm * Cc * 2);
  u16* ctxb = (u16*)alloc((size_t)Mm * Cc * 2);
  float* x2 = (float*)alloc((size_t)Mm * Cc * 4);
  float* xn = (float*)alloc((size_t)Mm * Cc * 4);
  u16* xnb  = (u16*)alloc((size_t)Mm * Cc * 2);
  float* x3 = (float*)alloc((size_t)Mm * Cc * 4);
  u16* x3b  = (u16*)alloc((size_t)Mm * Cc * 2);
  float* biasCat = (float*)alloc(1600 * 4);
  float* stats = (float*)alloc(4096);
  // attention scratch; xp aliases the pO region (distinct phases)
  const size_t FIXED = 26214400;  // qkb 10.49M + kb/vtb/ob 5.24M each
  const size_t POSZ = (size_t)KVS * Bb * Nn * Cc * 4;  // 41.94 MB
  const size_t SCRSZ = FIXED + POSZ + 524288;
  char* SCR = (char*)alloc(SCRSZ);
  u16* qkb = (u16*)SCR;                  // [M][640] (self qkv) / [M][320] (cross q)
  u16* kb  = (u16*)(SCR + 10485760);     // [M][320]
  u16* vtb = (u16*)(SCR + 15728640);     // [b][Cc][Nn]
  u16* ob  = (u16*)(SCR + 20971520);     // [M][Cc]
  char* REST = SCR + FIXED;
  float* pO  = (float*)REST;                     // flash partials
  float* pml = (float*)(REST + POSZ);            // 256 KB
  u16* xp = (u16*)REST;                          // [M][2560] (FFN phase)
  u16* ffb = (u16*)x2;  // [M][1280] aliases x2+xn (both dead by FFN phase)

  if (base == nullptr || ws_size < o) return;  // d_out stays poisoned

  const float scale = 1.0f / sqrtf((float)Cc);
  u16* wT[8];
  for (int i = 0; i < 8; ++i) wT[i] = wTall + (size_t)i * 320 * 320;

  // ---- prep: casts, weight transposes, bias concat ----
  cast_b<<<(Mm * Cc) / 1024, 256, 0, stream>>>(x, xb);
  cast_b<<<(Mm * Cc) / 1024, 256, 0, stream>>>(ctx, ctxb);
  {
    P8 ps;
    for (int i = 0; i < 8; ++i) ps.p[i] = W[i];
    tran8<<<dim3(10, 10, 8), dim3(32, 8), 0, stream>>>(ps, wTall);
  }
  tran_f2b<<<dim3(80, 10), dim3(32, 8), 0, stream>>>(gw, gwT, 320, 2560);
  tran_f2b<<<dim3(10, 40), dim3(32, 8), 0, stream>>>(dw, dwT, 1280, 320);
  prep_bias<<<7, 256, 0, stream>>>(Bv[0], Bv[1], Bv[2], Bv[5], Bv[6], biasCat);

  // ---- self-attention ----
  // fused q|k|v projection: N=960, B = [wq;wk;wv] (wTall contiguous),
  // cols<640 -> qkb [M][640]; cols>=640 -> vtb transposed
  gemm_nt<128, false, false, true><<<dim3(15, 64, 1), 256, 0, stream>>>(
      xb, Cc, 0, wT[0], Cc, 0, biasCat, nullptr, 0.f, nullptr, qkb, 640, 0,
      nullptr, vtb, 640, Cc, 1.f);
  flash_k<<<dim3(Nn / 64, KVS, Bb), 256, 0, stream>>>(qkb, 640, qkb + 320, 640,
                                                      vtb, pO, pml, scale);
  fcomb<<<Mm / 8, 256, 0, stream>>>(pO, pml, ob);
  // x2 = o@Wp + bp + 2*x  (BM=64: 640 blocks for occupancy)
  gemm_nt<64, true, false, false><<<dim3(5, 128, 1), 256, 0, stream>>>(
      ob, Cc, 0, wT[3], Cc, 0, Bv[3], x, 2.0f, nullptr, x2, Cc, 0, nullptr,
      nullptr, 0, Cc, 1.f);

  // ---- GroupNorm(x2) -> xn (fp32) + xnb (bf16) ----
  gn_stats<<<Bb * GROUPS * GN_SPLIT, 256, 0, stream>>>(x2, stats);
  gn_apply<<<(Mm * Cc) / 256, 256, 0, stream>>>(x2, stats, gn_g, gn_b, xn, xnb);

  // ---- cross-attention ----
  // q projection from xnb (N=320, BM=64)
  gemm_nt<64, false, false, false><<<dim3(5, 128, 1), 256, 0, stream>>>(
      xnb, Cc, 0, wT[4], Cc, 0, Bv[4], nullptr, 0.f, nullptr, qkb, 320, 0,
      nullptr, nullptr, 0, Cc, 1.f);
  // fused k|v projection from ctxb: N=640, cols<320 -> kb; cols>=320 -> vtb
  gemm_nt<128, false, false, true><<<dim3(10, 64, 1), 256, 0, stream>>>(
      ctxb, Cc, 0, wT[5], Cc, 0, biasCat + 960, nullptr, 0.f, nullptr, kb, 320,
      0, nullptr, vtb, 320, Cc, 1.f);
  flash_k<<<dim3(Nn / 64, KVS, Bb), 256, 0, stream>>>(qkb, 320, kb, 320, vtb,
                                                      pO, pml, scale);
  fcomb<<<Mm / 8, 256, 0, stream>>>(pO, pml, ob);
  // x3 = o@Wp2 + bp2 + xn + x2 (fp32 + bf16 dual, BM=64)
  gemm_nt<64, true, true, false><<<dim3(5, 128, 1), 256, 0, stream>>>(
      ob, Cc, 0, wT[7], Cc, 0, Bv[7], xn, 1.0f, x2, x3, Cc, 0, x3b, nullptr, 0,
      Cc, 1.f);

  // ---- GEGLU FFN: fused N=2560 gemm -> xp; comb -> ffb; dense -> out ----
  gemm_nt<128, false, false, false><<<dim3(40, 64, 1), 256, 0, stream>>>(
      x3b, Cc, 0, gwT, Cc, 0, gb, nullptr, 0.f, nullptr, xp, 2560, 0, nullptr,
      nullptr, 0, Cc, 1.f);
  geglu_comb<<<(int)(((size_t)Mm * 1280) / 1024), 256, 0, stream>>>(xp, ffb);
  gemm_nt<64, true, false, false><<<dim3(5, 128, 1), 256, 0, stream>>>(
      ffb, 1280, 0, dwT, 1280, 0, db, x3, 1.0f, nullptr, out, Cc, 0, nullptr,
      nullptr, 0, 1280, 1.f);
}